// Round 6
// baseline (419.664 us; speedup 1.0000x reference)
//
#include <hip/hip_runtime.h>
#include <cmath>

#define B_   4
#define N_   2466
#define R_   (B_*N_)     // 9864
#define ELLW 96

typedef _Float16 f16x8 __attribute__((ext_vector_type(8)));
typedef _Float16 f16x4 __attribute__((ext_vector_type(4)));
typedef __attribute__((ext_vector_type(4))) float f32x4;

__device__ __forceinline__ unsigned short f16_bits(float x) {
  union { _Float16 h; unsigned short u; } c;
  c.h = (_Float16)x;          // RNE
  return c.u;
}

struct WMats { const float* p[15]; };   // rb-major: w00,w01,pw,w10,w11

// Fragment-order layout (lin_w and res weights), f16 single-pass:
// e = ((slab*8 + nt)*64 + lane)*8 + j ; k = slab*32 + (lane>>4)*8 + j ; n = nt*16 + (lane&15)
// All activations AND split-K partials stored f16; all adds fp32. Rounding points
// identical to the 16-dispatch baseline => bit-identical output.
//
// xg (gathered align features) fragment layout:
//   xg[(((mtile*120 + slab)*64 + q*16 + l15)*8 + j] = feature[row = mtile*16+l15][k = slab*32+q*8+j]
// so an MFMA A-fragment load is xg + ((mtile*120+slab)*64 + lane)*8 — fully coalesced.

// ============ fused pre-kernel: transposes(->f16, 64x64 tiles) + ELL + W f16 splits ============
__global__ __launch_bounds__(256) void k_pre(
    const float* __restrict__ c2, const float* __restrict__ c3,
    const float* __restrict__ c4, const float* __restrict__ c5,
    unsigned short* __restrict__ t0, unsigned short* __restrict__ t1,
    unsigned short* __restrict__ t2, unsigned short* __restrict__ t3,
    const float* __restrict__ adj, int* __restrict__ cols, int* __restrict__ cnts,
    const float* __restrict__ lin_w,
    unsigned short* __restrict__ whf,
    WMats wm,
    unsigned short* __restrict__ wrf) {
  __shared__ float t[64][66];
  int bid = blockIdx.x;
  int tid = threadIdx.x;
  if (bid < 1584) {
    const float* in; unsigned short* out; int C, P, npb, ncb, rem;
    if (bid < 784)       { in = c2; out = t0; C = 256;  P = 3136; npb = 49; ncb = 4;  rem = bid; }
    else if (bid < 1200) { in = c3; out = t1; C = 512;  P = 784;  npb = 13; ncb = 8;  rem = bid - 784; }
    else if (bid < 1456) { in = c4; out = t2; C = 1024; P = 196;  npb = 4;  ncb = 16; rem = bid - 1200; }
    else                 { in = c5; out = t3; C = 2048; P = 49;   npb = 1;  ncb = 32; rem = bid - 1456; }
    int pb = rem % npb; int tq = rem / npb; int cb = tq % ncb; int b = tq / ncb;
    int c0 = cb * 64, p0 = pb * 64;
    #pragma unroll
    for (int i = 0; i < 8; i++) {
      int e = tid + i * 256;
      int c = e >> 5, f2 = e & 31;
      int p = p0 + f2 * 2;
      float2 v = make_float2(0.f, 0.f);
      const float* src = in + ((size_t)b * C + (c0 + c)) * P + p;
      if (p + 1 < P)      v = *(const float2*)src;
      else if (p < P)     v.x = *src;
      *(float2*)&t[c][f2 * 2] = v;
    }
    __syncthreads();
    int jj = tid & 15, c4i = jj * 4;
    #pragma unroll
    for (int pass = 0; pass < 4; pass++) {
      int pp = pass * 16 + (tid >> 4);
      int px = p0 + pp;
      if (px < P) {
        ushort4 o;
        o.x = f16_bits(t[c4i + 0][pp]);
        o.y = f16_bits(t[c4i + 1][pp]);
        o.z = f16_bits(t[c4i + 2][pp]);
        o.w = f16_bits(t[c4i + 3][pp]);
        *(ushort4*)&out[((size_t)b * P + px) * C + c0 + c4i] = o;
      }
    }
  } else if (bid < 4050) {
    int wave = tid >> 6, lane = tid & 63;
    int row = (bid - 1584) * 4 + wave;
    const float* Ar = adj + (size_t)row * N_;
    int* cp = cols + (size_t)row * ELLW;
    unsigned long long below = (lane == 63) ? 0xFFFFFFFFFFFFFFFFull >> 1
                                            : ((1ull << lane) - 1ull);
    float4 v[10];
    #pragma unroll
    for (int i0 = 0; i0 < 10; i0++) {
      int j0 = i0 * 256 + lane * 4;
      if (j0 + 3 < N_) {
        v[i0] = *(const float4*)&Ar[j0];
      } else {
        v[i0] = make_float4(0.f, 0.f, 0.f, 0.f);
        if (j0     < N_) v[i0].x = Ar[j0];
        if (j0 + 1 < N_) v[i0].y = Ar[j0+1];
        if (j0 + 2 < N_) v[i0].z = Ar[j0+2];
      }
    }
    int base = 0;
    #pragma unroll
    for (int i0 = 0; i0 < 10; i0++) {
      int j0 = i0 * 256 + lane * 4;
      bool nz0 = (j0     < N_) && (v[i0].x != 0.f);
      bool nz1 = (j0 + 1 < N_) && (v[i0].y != 0.f);
      bool nz2 = (j0 + 2 < N_) && (v[i0].z != 0.f);
      bool nz3 = (j0 + 3 < N_) && (v[i0].w != 0.f);
      unsigned long long m0 = __ballot(nz0);
      unsigned long long m1 = __ballot(nz1);
      unsigned long long m2 = __ballot(nz2);
      unsigned long long m3 = __ballot(nz3);
      int pre = __popcll(m0 & below) + __popcll(m1 & below)
              + __popcll(m2 & below) + __popcll(m3 & below);
      int p0 = base + pre;
      int p1 = p0 + (nz0 ? 1 : 0);
      int p2 = p1 + (nz1 ? 1 : 0);
      int p3 = p2 + (nz2 ? 1 : 0);
      if (nz0 && p0 < ELLW) cp[p0] = j0;
      if (nz1 && p1 < ELLW) cp[p1] = j0 + 1;
      if (nz2 && p2 < ELLW) cp[p2] = j0 + 2;
      if (nz3 && p3 < ELLW) cp[p3] = j0 + 3;
      base += __popcll(m0) + __popcll(m1) + __popcll(m2) + __popcll(m3);
    }
    if (lane == 0) cnts[row] = (base > ELLW) ? ELLW : base;
  } else if (bid < 4530) {
    int b = bid - 4050;
    int e0 = (b * 256 + tid) * 4;
    #pragma unroll
    for (int u = 0; u < 4; u++) {
      int e = e0 + u;
      int j = e & 7;
      int lane = (e >> 3) & 63;
      int nt = (e >> 9) & 7;
      int slab = e >> 12;
      int k = slab * 32 + ((lane >> 4) << 3) + j;
      int n = nt * 16 + (lane & 15);
      whf[e] = f16_bits(lin_w[(size_t)k * 128 + n]);
    }
  } else {
    int b = bid - 4530;
    int e0 = (b * 256 + tid) * 4;
    #pragma unroll
    for (int u = 0; u < 4; u++) {
      int e = e0 + u;
      int rb, mat, rem, K;
      if (e < 143360) {
        rb = 0;
        if (e < 110592) { mat = e / 36864; rem = e - mat * 36864; K = 259; }
        else { int tt = e - 110592; mat = 3 + tt / 16384; rem = tt & 16383; K = 128; }
      } else {
        int tt = e - 143360;
        rb = 1 + tt / 81920;
        int r2 = tt % 81920;
        mat = r2 / 16384; rem = r2 & 16383; K = 128;
      }
      int j = rem & 7, lane = (rem >> 3) & 63, nt = (rem >> 9) & 7, slab = rem >> 12;
      int k = slab * 32 + ((lane >> 4) << 3) + j;
      int n = nt * 16 + (lane & 15);
      float x = (k < K) ? wm.p[rb * 5 + mat][(size_t)k * 128 + n] : 0.f;
      wrf[e] = f16_bits(x);
    }
  }
}

// ============ vertex-align gather: tr maps -> xg (fragment order), coalesced reads ============
// 8 rows/block, 32 lanes/row. Per iteration i the 32 lanes cover k0 = (i*32+ln)*8,
// one contiguous 512B run per row; map boundaries (256/768/1792) align to iterations
// so the map choice is wave-uniform. Values are bit-copied f16 (or 0 when w==0 /
// pad row) — identical inputs to MFMA as the old scattered loads.
__global__ __launch_bounds__(256) void k_gather(
    const unsigned short* __restrict__ tr0, const unsigned short* __restrict__ tr1,
    const unsigned short* __restrict__ tr2, const unsigned short* __restrict__ tr3,
    const float* __restrict__ pos, unsigned short* __restrict__ xg) {
  int grp = threadIdx.x >> 5, ln = threadIdx.x & 31;
  int row = blockIdx.x * 8 + grp;           // grid 1248 -> rows 0..9983 (>=R_ zero pad)
  int mtile = row >> 4, l15 = row & 15;
  int zero[4]; int base[4];
  if (row < R_) {
    int b = row / N_;
    float px = pos[row*3+0], py = pos[row*3+1], pz = pos[row*3+2];
    float hh = fminf(fmaxf(248.f*(py/pz)    + 111.5f, 0.f), 223.f);
    float wc = fminf(fmaxf(248.f*(px/(-pz)) + 111.5f, 0.f), 223.f);
    const int Sarr[4] = {56, 28, 14, 7};
    const int Carr[4] = {256, 512, 1024, 2048};
    #pragma unroll
    for (int sc = 0; sc < 4; sc++) {
      int S = Sarr[sc], C = Carr[sc];
      float dv = 224.f / (float)S;
      float x = hh / dv, y = wc / dv;
      int x1 = (int)floorf(x), y1 = (int)floorf(y);
      int x2 = min((int)ceilf(x), S - 1), y2 = min((int)ceilf(y), S - 1);
      int w = (x2 - x1) * (y2 - y1);        // ∈ {0,1}
      zero[sc] = (w == 0);
      base[sc] = (b * S * S + x1 * S + y1) * C;
    }
  } else {
    zero[0] = zero[1] = zero[2] = zero[3] = 1;
    base[0] = base[1] = base[2] = base[3] = 0;
  }
  #pragma unroll
  for (int i = 0; i < 15; i++) {
    int k0 = (i * 32 + ln) * 8;             // 0..3832 step 8
    const unsigned short* tr; int off, sI;
    if (k0 < 256)       { tr = tr0; off = 0;    sI = 0; }
    else if (k0 < 768)  { tr = tr1; off = 256;  sI = 1; }
    else if (k0 < 1792) { tr = tr2; off = 768;  sI = 2; }
    else                { tr = tr3; off = 1792; sI = 3; }
    f16x8 v;
    if (zero[sI]) v = (f16x8)(_Float16)0;
    else          v = *(const f16x8*)(tr + base[sI] + (k0 - off));
    int slab = k0 >> 5, q = (k0 >> 3) & 3;
    *(f16x8*)&xg[(((size_t)mtile * 120 + slab) * 64 + q * 16 + l15) * 8] = v;
  }
}

// ============ split-K f16 MFMA GEMM from xg (coalesced A), f16 partials ============
// Same split boundaries, MFMA order and f16 partial rounding as before => bit-identical.
__global__ __launch_bounds__(256) void k_align_mfma(
    const unsigned short* __restrict__ xg,
    const unsigned short* __restrict__ whf,
    unsigned short* __restrict__ part, int kchunk) {
  int tid  = threadIdx.x;
  int wave = tid >> 6, lane = tid & 63;
  int q    = lane >> 4, l15 = lane & 15;
  int m0   = blockIdx.x * 128;
  int s    = blockIdx.y;
  int mt0  = blockIdx.x * 8 + wave * 2;     // mtile for u=0; u=1 is mt0+1

  f32x4 acc[2][8];
  #pragma unroll
  for (int u = 0; u < 2; u++)
    #pragma unroll
    for (int nt = 0; nt < 8; nt++) acc[u][nt] = (f32x4){0.f, 0.f, 0.f, 0.f};

  const f16x8* BH = (const f16x8*)whf;
  const f16x8* XG = (const f16x8*)xg;

  int kbeg = s * kchunk, kend = kbeg + kchunk;
  #pragma unroll 1
  for (int k0 = kbeg; k0 < kend; k0 += 32) {
    int slab = k0 >> 5;
    f16x8 af0 = XG[((size_t)(mt0 + 0) * 120 + slab) * 64 + lane];
    f16x8 af1 = XG[((size_t)(mt0 + 1) * 120 + slab) * 64 + lane];
    f16x8 Bh[8];
    #pragma unroll
    for (int nt = 0; nt < 8; nt++)
      Bh[nt] = BH[(size_t)(slab * 8 + nt) * 64 + lane];
    #pragma unroll
    for (int nt = 0; nt < 8; nt++) {
      acc[0][nt] = __builtin_amdgcn_mfma_f32_16x16x32_f16(af0, Bh[nt], acc[0][nt], 0, 0, 0);
      acc[1][nt] = __builtin_amdgcn_mfma_f32_16x16x32_f16(af1, Bh[nt], acc[1][nt], 0, 0, 0);
    }
  }

  #pragma unroll
  for (int u = 0; u < 2; u++)
    #pragma unroll
    for (int nt = 0; nt < 8; nt++)
      #pragma unroll
      for (int r = 0; r < 4; r++) {
        int row = m0 + (wave * 2 + u) * 16 + q * 4 + r;
        if (row < R_)
          part[((size_t)s * R_ + row) * 128 + nt * 16 + l15] = f16_bits(acc[u][nt][r]);
      }
}

// ---------------- reduce f16 partials(fp32 adds) + bias -> xcat f16 ----------------
__global__ __launch_bounds__(256) void k_reduce(
    const unsigned short* __restrict__ part, const float* __restrict__ lin_b,
    const float* __restrict__ vf, const float* __restrict__ pos,
    unsigned short* __restrict__ xcat, int nsplit) {
  int grp = threadIdx.x >> 5, ln = threadIdx.x & 31;
  int row = blockIdx.x * 8 + grp;           // 1233*8 = 9864
  float4 acc = ((const float4*)lin_b)[ln];
  const f16x4* p4 = (const f16x4*)part;
  for (int s = 0; s < nsplit; s++) {
    f16x4 pv = p4[((size_t)s * R_ + row) * 32 + ln];
    acc.x += (float)pv[0]; acc.y += (float)pv[1];
    acc.z += (float)pv[2]; acc.w += (float)pv[3];
  }
  ushort4* xr = (ushort4*)(xcat + (size_t)row * 288);
  ushort4 o;
  o.x = f16_bits(acc.x); o.y = f16_bits(acc.y);
  o.z = f16_bits(acc.z); o.w = f16_bits(acc.w);
  xr[ln] = o;
  float4 vv = ((const float4*)vf)[(size_t)row * 32 + ln];
  o.x = f16_bits(vv.x); o.y = f16_bits(vv.y);
  o.z = f16_bits(vv.z); o.w = f16_bits(vv.w);
  xr[32 + ln] = o;
  if (ln < 8) {
    ushort4 z = make_ushort4(0, 0, 0, 0);
    if (ln == 0) {
      z.x = f16_bits(pos[(size_t)row * 3 + 0]);
      z.y = f16_bits(pos[(size_t)row * 3 + 1]);
      z.z = f16_bits(pos[(size_t)row * 3 + 2]);
    }
    xr[64 + ln] = z;
  }
}

// ============ f16 MFMA GEMM: out[which] = X @ W[which] (+pb for which==2) ============
template<int SLABS>
__global__ __launch_bounds__(256) void k_gemm_mfma(
    const unsigned short* __restrict__ X, int ldx,
    const unsigned short* __restrict__ wf,
    int matStride, const float* __restrict__ pb,
    unsigned short* __restrict__ o0, unsigned short* __restrict__ o1,
    unsigned short* __restrict__ o2) {
  int tid = threadIdx.x;
  int wave = tid >> 6, lane = tid & 63;
  int q = lane >> 4, l15 = lane & 15;
  int which = blockIdx.y;
  int m0 = blockIdx.x * 64;
  int mrow = m0 + wave * 16 + l15;
  int rowc = (mrow < R_) ? mrow : (R_ - 1);
  const unsigned short* xrow = X + (size_t)rowc * ldx + q * 8;

  const f16x8* BH = (const f16x8*)(wf + (size_t)which * matStride);

  f32x4 acc[8];
  #pragma unroll
  for (int nt = 0; nt < 8; nt++) acc[nt] = (f32x4){0.f, 0.f, 0.f, 0.f};

  #pragma unroll 1
  for (int slab = 0; slab < SLABS; slab++) {
    f16x8 af = *(const f16x8*)(xrow + slab * 32);
    f16x8 Bh[8];
    #pragma unroll
    for (int nt = 0; nt < 8; nt++)
      Bh[nt] = BH[(size_t)(slab * 8 + nt) * 64 + lane];
    #pragma unroll
    for (int nt = 0; nt < 8; nt++)
      acc[nt] = __builtin_amdgcn_mfma_f32_16x16x32_f16(af, Bh[nt], acc[nt], 0, 0, 0);
  }

  unsigned short* out = (which == 0) ? o0 : (which == 1) ? o1 : o2;
  #pragma unroll
  for (int nt = 0; nt < 8; nt++) {
    int col = nt * 16 + l15;
    float bias = (pb != nullptr && which == 2) ? pb[col] : 0.f;
    #pragma unroll
    for (int r = 0; r < 4; r++) {
      int row = m0 + wave * 16 + q * 4 + r;
      if (row < R_) out[(size_t)row * 128 + col] = f16_bits(acc[nt][r] + bias);
    }
  }
}

// ============ fused SpMM -> LDS -> GEMM ============
// Phase A: h = [skip? +] relu(s + A@t) for 32 rows, EXACT k_spmm arithmetic
//          (32 coalesced lanes per row, gather done ONCE per block), rounded
//          to f16 (same rounding point as the old hb store) into LDS.
// Phase B: out[which] = h @ W[which] (+pb for which==2), MFMA from LDS.
// Bit-identical to the separate spmm+gemm pair.
template<int NW>
__global__ __launch_bounds__(256) void k_fuse(
    const unsigned short* __restrict__ s_in,
    const unsigned short* __restrict__ t_in,
    const unsigned short* __restrict__ skip_in,
    const int* __restrict__ cols, const int* __restrict__ cnts,
    const unsigned short* __restrict__ wf, const float* __restrict__ pb,
    unsigned short* __restrict__ o0, unsigned short* __restrict__ o1,
    unsigned short* __restrict__ o2) {
  __shared__ unsigned short hsm[32][136];   // +8 pad: row stride 272B (17x16B) => 2-way banks
  int tid = threadIdx.x;
  int r0 = blockIdx.x * 32;

  // ---- phase A: gather 32 rows into LDS ----
  {
    int grp = tid >> 5, ln = tid & 31;
    const f16x4* s4 = (const f16x4*)s_in;
    const f16x4* t4 = (const f16x4*)t_in;
    #pragma unroll 1
    for (int rr = 0; rr < 4; rr++) {
      int lrow = grp * 4 + rr;
      int row = r0 + lrow;
      int rowc = (row < R_) ? row : (R_ - 1);
      int b = rowc / N_;
      size_t tbase = (size_t)b * N_;
      const int* cp = cols + (size_t)rowc * ELLW;
      int4 ci0 = *(const int4*)cp;
      int4 ci1 = *(const int4*)(cp + 4);
      int4 ci2 = *(const int4*)(cp + 8);
      int cnt = cnts[rowc];
      f16x4 sv = s4[(size_t)rowc*32 + ln];
      float4 acc = make_float4((float)sv[0], (float)sv[1], (float)sv[2], (float)sv[3]);
      int idx[12] = {ci0.x, ci0.y, ci0.z, ci0.w, ci1.x, ci1.y, ci1.z, ci1.w,
                     ci2.x, ci2.y, ci2.z, ci2.w};
      f16x4 g[12];
      #pragma unroll
      for (int i = 0; i < 12; i++) {
        int c = idx[i];
        c = (c >= 0 && c < N_) ? c : 0;
        g[i] = t4[(tbase + c)*32 + ln];
      }
      #pragma unroll
      for (int i = 0; i < 12; i++) {
        if (i < cnt) {
          acc.x += (float)g[i][0]; acc.y += (float)g[i][1];
          acc.z += (float)g[i][2]; acc.w += (float)g[i][3];
        }
      }
      for (int i = 12; i < cnt; i++) {
        f16x4 v = t4[(tbase + cp[i])*32 + ln];
        acc.x += (float)v[0]; acc.y += (float)v[1];
        acc.z += (float)v[2]; acc.w += (float)v[3];
      }
      acc.x = fmaxf(acc.x, 0.f); acc.y = fmaxf(acc.y, 0.f);
      acc.z = fmaxf(acc.z, 0.f); acc.w = fmaxf(acc.w, 0.f);
      if (skip_in) {
        f16x4 sk = ((const f16x4*)skip_in)[(size_t)rowc*32 + ln];
        acc.x += (float)sk[0]; acc.y += (float)sk[1];
        acc.z += (float)sk[2]; acc.w += (float)sk[3];
      }
      ushort4 o;
      o.x = f16_bits(acc.x); o.y = f16_bits(acc.y);
      o.z = f16_bits(acc.z); o.w = f16_bits(acc.w);
      *(ushort4*)&hsm[lrow][ln * 4] = o;
    }
  }
  __syncthreads();

  // ---- phase B: MFMA from LDS. wave = mtile (rows 16*mt..) x nt-half ----
  int wave = tid >> 6, lane = tid & 63;
  int q = lane >> 4, l15 = lane & 15;
  int mt = wave & 1, nh = wave >> 1;
  const unsigned short* xrow = &hsm[mt * 16 + l15][q * 8];

  #pragma unroll 1
  for (int which = 0; which < NW; which++) {
    const f16x8* BH = (const f16x8*)(wf + (size_t)which * 16384);
    f32x4 acc[4];
    #pragma unroll
    for (int t2 = 0; t2 < 4; t2++) acc[t2] = (f32x4){0.f, 0.f, 0.f, 0.f};
    #pragma unroll
    for (int slab = 0; slab < 4; slab++) {
      f16x8 af = *(const f16x8*)(xrow + slab * 32);
      f16x8 Bh[4];
      #pragma unroll
      for (int t2 = 0; t2 < 4; t2++)
        Bh[t2] = BH[(size_t)(slab * 8 + nh * 4 + t2) * 64 + lane];
      #pragma unroll
      for (int t2 = 0; t2 < 4; t2++)
        acc[t2] = __builtin_amdgcn_mfma_f32_16x16x32_f16(af, Bh[t2], acc[t2], 0, 0, 0);
    }
    unsigned short* out = (which == 0) ? o0 : (which == 1) ? o1 : o2;
    #pragma unroll
    for (int t2 = 0; t2 < 4; t2++) {
      int col = (nh * 4 + t2) * 16 + l15;
      float bias = (pb != nullptr && which == 2) ? pb[col] : 0.f;
      #pragma unroll
      for (int r = 0; r < 4; r++) {
        int row = r0 + mt * 16 + q * 4 + r;
        if (row < R_) out[(size_t)row * 128 + col] = f16_bits(acc[t2][r] + bias);
      }
    }
  }
}

// ---------------- SpMM (f16 in/out, fp32 adds): out = [skip +] relu(s + A@t) ----------------
__global__ __launch_bounds__(256) void k_spmm(
    const unsigned short* __restrict__ sb, const unsigned short* __restrict__ tb,
    const int* __restrict__ cols, const int* __restrict__ cnts,
    const unsigned short* __restrict__ skipb, unsigned short* __restrict__ outb,
    const float* __restrict__ gw0, const float* __restrict__ gw1,
    unsigned short* __restrict__ gsb, unsigned short* __restrict__ gtb, int fuse_gf) {
  int tid = threadIdx.x;
  int grp = tid >> 5, ln = tid & 31;
  int row = blockIdx.x * 8 + grp;           // 1233 * 8 = 9864 exact
  int b = row / N_;
  size_t tbase = (size_t)b * N_;
  const f16x4* sb4 = (const f16x4*)sb;
  const f16x4* tb4 = (const f16x4*)tb;
  const int* cp = cols + (size_t)row * ELLW;
  int4 ci0 = *(const int4*)cp;
  int4 ci1 = *(const int4*)(cp + 4);
  int4 ci2 = *(const int4*)(cp + 8);
  int cnt = cnts[row];
  f16x4 sv = sb4[(size_t)row*32 + ln];
  float4 acc = make_float4((float)sv[0], (float)sv[1], (float)sv[2], (float)sv[3]);
  int idx[12] = {ci0.x, ci0.y, ci0.z, ci0.w, ci1.x, ci1.y, ci1.z, ci1.w,
                 ci2.x, ci2.y, ci2.z, ci2.w};
  f16x4 g[12];
  #pragma unroll
  for (int i = 0; i < 12; i++) {
    int c = idx[i];
    c = (c >= 0 && c < N_) ? c : 0;
    g[i] = tb4[(tbase + c)*32 + ln];
  }
  #pragma unroll
  for (int i = 0; i < 12; i++) {
    if (i < cnt) {
      acc.x += (float)g[i][0]; acc.y += (float)g[i][1];
      acc.z += (float)g[i][2]; acc.w += (float)g[i][3];
    }
  }
  for (int i = 12; i < cnt; i++) {
    f16x4 v = tb4[(tbase + cp[i])*32 + ln];
    acc.x += (float)v[0]; acc.y += (float)v[1];
    acc.z += (float)v[2]; acc.w += (float)v[3];
  }
  acc.x = fmaxf(acc.x, 0.f); acc.y = fmaxf(acc.y, 0.f);
  acc.z = fmaxf(acc.z, 0.f); acc.w = fmaxf(acc.w, 0.f);
  if (skipb) {
    f16x4 sk = ((const f16x4*)skipb)[(size_t)row*32 + ln];
    acc.x += (float)sk[0]; acc.y += (float)sk[1];
    acc.z += (float)sk[2]; acc.w += (float)sk[3];
  }
  if (!fuse_gf) {
    ushort4 o;
    o.x = f16_bits(acc.x); o.y = f16_bits(acc.y);
    o.z = f16_bits(acc.z); o.w = f16_bits(acc.w);
    ((ushort4*)outb)[(size_t)row*32 + ln] = o;
    return;
  }
  float av[4] = {acc.x, acc.y, acc.z, acc.w};
  int j0 = ln * 4;
  float p0 = 0.f, p1 = 0.f, p2 = 0.f, q0 = 0.f, q1 = 0.f, q2 = 0.f;
  #pragma unroll
  for (int u = 0; u < 4; u++) {
    int j = j0 + u;
    p0 += av[u] * gw0[j*3+0]; p1 += av[u] * gw0[j*3+1]; p2 += av[u] * gw0[j*3+2];
    q0 += av[u] * gw1[j*3+0]; q1 += av[u] * gw1[j*3+1]; q2 += av[u] * gw1[j*3+2];
  }
  #pragma unroll
  for (int off = 16; off >= 1; off >>= 1) {
    p0 += __shfl_xor(p0, off); p1 += __shfl_xor(p1, off); p2 += __shfl_xor(p2, off);
    q0 += __shfl_xor(q0, off); q1 += __shfl_xor(q1, off); q2 += __shfl_xor(q2, off);
  }
  if (ln == 0) {
    gsb[(size_t)row*128 + 0] = f16_bits(p0);
    gsb[(size_t)row*128 + 1] = f16_bits(p1);
    gsb[(size_t)row*128 + 2] = f16_bits(p2);
    gtb[(size_t)row*128 + 0] = f16_bits(q0);
    gtb[(size_t)row*128 + 1] = f16_bits(q1);
    gtb[(size_t)row*128 + 2] = f16_bits(q2);
  }
}

// ---------------- final: out = pos + tanh(relu(s + A@t)), f16 in, fp32 out ----------------
__global__ __launch_bounds__(256) void k_gf_final(
    const unsigned short* __restrict__ sb, const unsigned short* __restrict__ tb,
    const int* __restrict__ cols, const int* __restrict__ cnts,
    const float* __restrict__ pos, float* __restrict__ out) {
  int wave = threadIdx.x >> 6, lane = threadIdx.x & 63;
  int row = blockIdx.x * 4 + wave;          // grid 2466
  if (lane >= 3) return;
  int b = row / N_;
  size_t tbase = (size_t)b * N_;
  const int* cp = cols + (size_t)row * ELLW;
  int4 ci0 = *(const int4*)cp;
  int4 ci1 = *(const int4*)(cp + 4);
  int4 ci2 = *(const int4*)(cp + 8);
  int cnt = cnts[row];
  union { unsigned short u; _Float16 h; } cv;
  cv.u = sb[(size_t)row*128 + lane];
  float acc = (float)cv.h;
  int idx[12] = {ci0.x, ci0.y, ci0.z, ci0.w, ci1.x, ci1.y, ci1.z, ci1.w,
                 ci2.x, ci2.y, ci2.z, ci2.w};
  float g[12];
  #pragma unroll
  for (int i = 0; i < 12; i++) {
    int c = idx[i];
    c = (c >= 0 && c < N_) ? c : 0;
    cv.u = tb[(tbase + c)*128 + lane];
    g[i] = (float)cv.h;
  }
  #pragma unroll
  for (int i = 0; i < 12; i++)
    if (i < cnt) acc += g[i];
  for (int i = 12; i < cnt; i++) {
    cv.u = tb[(tbase + cp[i])*128 + lane];
    acc += (float)cv.h;
  }
  float v = tanhf(fmaxf(acc, 0.f));
  out[(size_t)row*3 + lane] = pos[(size_t)row*3 + lane] + v;
}

extern "C" void kernel_launch(void* const* d_in, const int* in_sizes, int n_in,
                              void* d_out, int out_size, void* d_ws, size_t ws_size,
                              hipStream_t stream) {
  const float* conv2_3 = (const float*)d_in[0];
  const float* conv3_4 = (const float*)d_in[1];
  const float* conv4_6 = (const float*)d_in[2];
  const float* conv5_3 = (const float*)d_in[3];
  const float* pos     = (const float*)d_in[4];
  const float* vf      = (const float*)d_in[5];
  const float* adj     = (const float*)d_in[6];
  const float* lin_w   = (const float*)d_in[7];
  const float* lin_b   = (const float*)d_in[8];
  const float* r_pb[3]  = {(const float*)d_in[10], (const float*)d_in[16], (const float*)d_in[22]};
  const float* gf_w0 = (const float*)d_in[27];
  const float* gf_w1 = (const float*)d_in[28];
  float* out = (float*)d_out;

  // ---- workspace layout (all segments 16B-aligned; everything f16 except ELL ints) ----
  const size_t ROWF    = (size_t)R_ * 128;        // elems per activation buffer
  const size_t XCATE   = (size_t)R_ * 288;
  const size_t LINW_E  = 491520;
  const size_t RESW_E  = 307200;
  const size_t XG_E    = (size_t)624 * 120 * 512; // 38,338,560 elems (76.7 MB)

  unsigned short* trh0 = (unsigned short*)d_ws;
  unsigned short* trh1 = trh0 + (size_t)4*256*3136;
  unsigned short* trh2 = trh1 + (size_t)4*512*784;
  unsigned short* trh3 = trh2 + (size_t)4*1024*196;
  int*   ell_cnt  = (int*)(trh3 + (size_t)4*2048*49);
  int*   ell_cols = ell_cnt + R_;
  unsigned short* whf = (unsigned short*)(ell_cols + (size_t)R_*ELLW);
  unsigned short* wrf = whf + LINW_E;
  unsigned short* part = wrf + RESW_E + 512;      // f16 split-K partials

  size_t fixed_h = 6021120 + 2*(size_t)R_*(ELLW+1) + LINW_E + RESW_E + 512;  // shorts
  size_t need8 = (fixed_h + (size_t)8*ROWF + XCATE + 8*ROWF + XG_E + 1024) * 2;  // bytes
  int nsplit = (ws_size >= need8) ? 8 : 4;
  int kchunk = 3840 / nsplit;

  unsigned short* xcat = part + (size_t)nsplit * ROWF;
  unsigned short* sb   = xcat + XCATE;
  unsigned short* tb   = sb   + ROWF;
  unsigned short* sb2  = tb   + ROWF;
  unsigned short* tb2  = sb2  + ROWF;
  unsigned short* skA  = tb2  + ROWF;
  unsigned short* skB  = skA  + ROWF;
  unsigned short* gsb  = skB  + ROWF;
  unsigned short* gtb  = gsb  + ROWF;
  unsigned short* xg   = gtb  + ROWF;             // fragment-order gathered features

  WMats wm;
  for (int rb = 0; rb < 3; rb++) {
    wm.p[rb*5 + 0] = (const float*)d_in[11 + 6*rb];  // w00
    wm.p[rb*5 + 1] = (const float*)d_in[12 + 6*rb];  // w01
    wm.p[rb*5 + 2] = (const float*)d_in[9  + 6*rb];  // pw
    wm.p[rb*5 + 3] = (const float*)d_in[13 + 6*rb];  // w10
    wm.p[rb*5 + 4] = (const float*)d_in[14 + 6*rb];  // w11
  }

  const int NFB = (R_ + 31) / 32;   // 309 fuse blocks

  // D0: transposes(->f16) + ELL + all W f16 splits
  k_pre<<<4830, 256, 0, stream>>>(conv2_3, conv3_4, conv4_6, conv5_3,
                                  trh0, trh1, trh2, trh3,
                                  adj, ell_cols, ell_cnt,
                                  lin_w, whf, wm, wrf);

  // D1a: gather tr maps -> xg (fragment order, coalesced reads)
  k_gather<<<1248, 256, 0, stream>>>(trh0, trh1, trh2, trh3, pos, xg);

  // D1b: split-K f16 MFMA align GEMM from xg (coalesced A; f16 partials)
  k_align_mfma<<<dim3(78, nsplit), 256, 0, stream>>>(xg, whf, part, kchunk);

  // D2: reduce f16 partials + concat -> xcat
  k_reduce<<<1233, 256, 0, stream>>>(part, lin_b, vf, pos, xcat, nsplit);

  // D3: rb0 GEMM1: xcat @ {w00,w01,pw} -> sb,tb,skA
  k_gemm_mfma<9><<<dim3(155, 3), 256, 0, stream>>>(
      xcat, 288, wrf + 0, 36864, r_pb[0], sb, tb, skA);

  // D4: rb0 [spmm1+GEMM2]: h=relu(sb+A tb); h @ {w10,w11} -> sb2,tb2
  k_fuse<2><<<NFB, 256, 0, stream>>>(sb, tb, nullptr, ell_cols, ell_cnt,
                                     wrf + 110592, nullptr, sb2, tb2, nullptr);

  // D5: rb1 [spmm2+GEMM1]: x=skA+relu(sb2+A tb2); x @ {w00,w01,pw} -> sb,tb,skB
  k_fuse<3><<<NFB, 256, 0, stream>>>(sb2, tb2, skA, ell_cols, ell_cnt,
                                     wrf + 143360, r_pb[1], sb, tb, skB);

  // D6: rb1 [spmm1+GEMM2] -> sb2,tb2
  k_fuse<2><<<NFB, 256, 0, stream>>>(sb, tb, nullptr, ell_cols, ell_cnt,
                                     wrf + 192512, nullptr, sb2, tb2, nullptr);

  // D7: rb2 [spmm2+GEMM1]: x=skB+relu(...); -> sb,tb,skA
  k_fuse<3><<<NFB, 256, 0, stream>>>(sb2, tb2, skB, ell_cols, ell_cnt,
                                     wrf + 225280, r_pb[2], sb, tb, skA);

  // D8: rb2 [spmm1+GEMM2] -> sb2,tb2
  k_fuse<2><<<NFB, 256, 0, stream>>>(sb, tb, nullptr, ell_cols, ell_cnt,
                                     wrf + 274432, nullptr, sb2, tb2, nullptr);

  // D9: x_next = skA + relu(sb2 + A tb2); gsb = x@gf_w0, gtb = x@gf_w1
  k_spmm<<<1233, 256, 0, stream>>>(sb2, tb2, ell_cols, ell_cnt, skA, nullptr,
                                   gf_w0, gf_w1, gsb, gtb, 1);

  // D10: out = pos + tanh(relu(gsb + A gtb))
  k_gf_final<<<2466, 256, 0, stream>>>(gsb, gtb, ell_cols, ell_cnt, pos, out);
}

// Round 7
// 349.191 us; speedup vs baseline: 1.2018x; 1.2018x over previous
//
#include <hip/hip_runtime.h>
#include <cmath>

#define B_   4
#define N_   2466
#define R_   (B_*N_)     // 9864
#define ELLW 96

typedef _Float16 f16x8 __attribute__((ext_vector_type(8)));
typedef _Float16 f16x4 __attribute__((ext_vector_type(4)));
typedef __attribute__((ext_vector_type(4))) float f32x4;

__device__ __forceinline__ unsigned short f16_bits(float x) {
  union { _Float16 h; unsigned short u; } c;
  c.h = (_Float16)x;          // RNE
  return c.u;
}

struct WMats { const float* p[15]; };   // rb-major: w00,w01,pw,w10,w11

// Fragment-order layout (lin_w and res weights), f16 single-pass:
// e = ((slab*8 + nt)*64 + lane)*8 + j ; k = slab*32 + (lane>>4)*8 + j ; n = nt*16 + (lane&15)
// All activations AND split-K partials stored f16; all adds fp32. Rounding points
// and add ORDER identical to the baseline => bit-identical output.

// ============ fused pre-kernel: transposes(->f16) + ELL(4-wave scan) + W f16 splits ============
// grid: [0,1584) transpose | [1584,11448) ELL one block PER ROW | [11448,11928) whf | rest wrf
__global__ __launch_bounds__(256) void k_pre(
    const float* __restrict__ c2, const float* __restrict__ c3,
    const float* __restrict__ c4, const float* __restrict__ c5,
    unsigned short* __restrict__ t0, unsigned short* __restrict__ t1,
    unsigned short* __restrict__ t2, unsigned short* __restrict__ t3,
    const float* __restrict__ adj, int* __restrict__ cols, int* __restrict__ cnts,
    const float* __restrict__ lin_w,
    unsigned short* __restrict__ whf,
    WMats wm,
    unsigned short* __restrict__ wrf) {
  __shared__ float t[64][66];
  int bid = blockIdx.x;
  int tid = threadIdx.x;
  if (bid < 1584) {
    const float* in; unsigned short* out; int C, P, npb, ncb, rem;
    if (bid < 784)       { in = c2; out = t0; C = 256;  P = 3136; npb = 49; ncb = 4;  rem = bid; }
    else if (bid < 1200) { in = c3; out = t1; C = 512;  P = 784;  npb = 13; ncb = 8;  rem = bid - 784; }
    else if (bid < 1456) { in = c4; out = t2; C = 1024; P = 196;  npb = 4;  ncb = 16; rem = bid - 1200; }
    else                 { in = c5; out = t3; C = 2048; P = 49;   npb = 1;  ncb = 32; rem = bid - 1456; }
    int pb = rem % npb; int tq = rem / npb; int cb = tq % ncb; int b = tq / ncb;
    int c0 = cb * 64, p0 = pb * 64;
    #pragma unroll
    for (int i = 0; i < 8; i++) {
      int e = tid + i * 256;
      int c = e >> 5, f2 = e & 31;
      int p = p0 + f2 * 2;
      float2 v = make_float2(0.f, 0.f);
      const float* src = in + ((size_t)b * C + (c0 + c)) * P + p;
      if (p + 1 < P)      v = *(const float2*)src;
      else if (p < P)     v.x = *src;
      *(float2*)&t[c][f2 * 2] = v;
    }
    __syncthreads();
    int jj = tid & 15, c4i = jj * 4;
    #pragma unroll
    for (int pass = 0; pass < 4; pass++) {
      int pp = pass * 16 + (tid >> 4);
      int px = p0 + pp;
      if (px < P) {
        ushort4 o;
        o.x = f16_bits(t[c4i + 0][pp]);
        o.y = f16_bits(t[c4i + 1][pp]);
        o.z = f16_bits(t[c4i + 2][pp]);
        o.w = f16_bits(t[c4i + 3][pp]);
        *(ushort4*)&out[((size_t)b * P + px) * C + c0 + c4i] = o;
      }
    }
  } else if (bid < 11448) {
    // ---- ELL: one block per row; 4 waves cover j-ranges of 640; 2-pass scan ----
    // Output order identical to the serial version: ascending j.
    int row = bid - 1584;
    int wv = tid >> 6, lane = tid & 63;
    const float* Ar = adj + (size_t)row * N_;
    int* cp = cols + (size_t)row * ELLW;
    unsigned long long below = (lane == 63) ? 0xFFFFFFFFFFFFFFFFull >> 1
                                            : ((1ull << lane) - 1ull);
    int jbeg = wv * 640;
    int jend = (jbeg + 640 < N_) ? jbeg + 640 : N_;
    unsigned long long m[3][4];
    int cnt = 0;
    #pragma unroll
    for (int i = 0; i < 3; i++) {
      int j0 = jbeg + i * 256 + lane * 4;
      float4 v = make_float4(0.f, 0.f, 0.f, 0.f);
      if (j0 + 3 < jend) {
        v = *(const float4*)&Ar[j0];
      } else {
        if (j0     < jend) v.x = Ar[j0];
        if (j0 + 1 < jend) v.y = Ar[j0+1];
        if (j0 + 2 < jend) v.z = Ar[j0+2];
      }
      m[i][0] = __ballot((j0     < jend) && (v.x != 0.f));
      m[i][1] = __ballot((j0 + 1 < jend) && (v.y != 0.f));
      m[i][2] = __ballot((j0 + 2 < jend) && (v.z != 0.f));
      m[i][3] = __ballot((j0 + 3 < jend) && (v.w != 0.f));
      cnt += __popcll(m[i][0]) + __popcll(m[i][1])
           + __popcll(m[i][2]) + __popcll(m[i][3]);
    }
    int* sc = (int*)&t[0][0];
    if (lane == 0) sc[wv] = cnt;
    __syncthreads();
    int base = 0;
    #pragma unroll
    for (int w2 = 0; w2 < 4; w2++) {
      int c = sc[w2];
      if (w2 < wv) base += c;
    }
    int tot = sc[0] + sc[1] + sc[2] + sc[3];
    int run = base;
    #pragma unroll
    for (int i = 0; i < 3; i++) {
      int j0 = jbeg + i * 256 + lane * 4;
      unsigned long long m0 = m[i][0], m1 = m[i][1], m2 = m[i][2], m3 = m[i][3];
      int pre = __popcll(m0 & below) + __popcll(m1 & below)
              + __popcll(m2 & below) + __popcll(m3 & below);
      bool nz0 = (m0 >> lane) & 1ull;
      bool nz1 = (m1 >> lane) & 1ull;
      bool nz2 = (m2 >> lane) & 1ull;
      bool nz3 = (m3 >> lane) & 1ull;
      int p0 = run + pre;
      int p1 = p0 + (nz0 ? 1 : 0);
      int p2 = p1 + (nz1 ? 1 : 0);
      int p3 = p2 + (nz2 ? 1 : 0);
      if (nz0 && p0 < ELLW) cp[p0] = j0;
      if (nz1 && p1 < ELLW) cp[p1] = j0 + 1;
      if (nz2 && p2 < ELLW) cp[p2] = j0 + 2;
      if (nz3 && p3 < ELLW) cp[p3] = j0 + 3;
      run += __popcll(m0) + __popcll(m1) + __popcll(m2) + __popcll(m3);
    }
    if (wv == 3 && lane == 0) cnts[row] = (tot > ELLW) ? ELLW : tot;
  } else if (bid < 11928) {
    int b = bid - 11448;
    int e0 = (b * 256 + tid) * 4;
    #pragma unroll
    for (int u = 0; u < 4; u++) {
      int e = e0 + u;
      int j = e & 7;
      int lane = (e >> 3) & 63;
      int nt = (e >> 9) & 7;
      int slab = e >> 12;
      int k = slab * 32 + ((lane >> 4) << 3) + j;
      int n = nt * 16 + (lane & 15);
      whf[e] = f16_bits(lin_w[(size_t)k * 128 + n]);
    }
  } else {
    int b = bid - 11928;
    int e0 = (b * 256 + tid) * 4;
    #pragma unroll
    for (int u = 0; u < 4; u++) {
      int e = e0 + u;
      int rb, mat, rem, K;
      if (e < 143360) {
        rb = 0;
        if (e < 110592) { mat = e / 36864; rem = e - mat * 36864; K = 259; }
        else { int tt = e - 110592; mat = 3 + tt / 16384; rem = tt & 16383; K = 128; }
      } else {
        int tt = e - 143360;
        rb = 1 + tt / 81920;
        int r2 = tt % 81920;
        mat = r2 / 16384; rem = r2 & 16383; K = 128;
      }
      int j = rem & 7, lane = (rem >> 3) & 63, nt = (rem >> 9) & 7, slab = rem >> 12;
      int k = slab * 32 + ((lane >> 4) << 3) + j;
      int n = nt * 16 + (lane & 15);
      float x = (k < K) ? wm.p[rb * 5 + mat][(size_t)k * 128 + n] : 0.f;
      wrf[e] = f16_bits(x);
    }
  }
}

// ============ split-K vertex-align gather (f16 maps) + f16 MFMA GEMM, f16 partials ============
__global__ __launch_bounds__(256) void k_align_mfma(
    const unsigned short* __restrict__ tr0, const unsigned short* __restrict__ tr1,
    const unsigned short* __restrict__ tr2, const unsigned short* __restrict__ tr3,
    const float* __restrict__ pos,
    const unsigned short* __restrict__ whf,
    unsigned short* __restrict__ part, int kchunk) {
  int tid  = threadIdx.x;
  int wave = tid >> 6, lane = tid & 63;
  int q    = lane >> 4, l15 = lane & 15;
  int m0   = blockIdx.x * 128;
  int s    = blockIdx.y;

  int zero[2][4]; int base[2][4];
  #pragma unroll
  for (int u = 0; u < 2; u++) {
    int mrow = m0 + (wave * 2 + u) * 16 + l15;
    int rowc = (mrow < R_) ? mrow : 0;
    int b = rowc / N_;
    float px = pos[rowc*3+0], py = pos[rowc*3+1], pz = pos[rowc*3+2];
    float hh = fminf(fmaxf(248.f*(py/pz)    + 111.5f, 0.f), 223.f);
    float wc = fminf(fmaxf(248.f*(px/(-pz)) + 111.5f, 0.f), 223.f);
    const int Sarr[4] = {56, 28, 14, 7};
    const int Carr[4] = {256, 512, 1024, 2048};
    #pragma unroll
    for (int sc = 0; sc < 4; sc++) {
      int S = Sarr[sc], C = Carr[sc];
      float dv = 224.f / (float)S;
      float x = hh / dv, y = wc / dv;
      int x1 = (int)floorf(x), y1 = (int)floorf(y);
      int x2 = min((int)ceilf(x), S - 1), y2 = min((int)ceilf(y), S - 1);
      int w = (x2 - x1) * (y2 - y1);              // ∈ {0,1}
      zero[u][sc] = (mrow >= R_) || (w == 0);
      base[u][sc] = (b * S * S + x1 * S + y1) * C;
    }
  }

  f32x4 acc[2][8];
  #pragma unroll
  for (int u = 0; u < 2; u++)
    #pragma unroll
    for (int nt = 0; nt < 8; nt++) acc[u][nt] = (f32x4){0.f, 0.f, 0.f, 0.f};

  const f16x8* BH = (const f16x8*)whf;

  int kbeg = s * kchunk, kend = kbeg + kchunk;
  #pragma unroll 1
  for (int k0 = kbeg; k0 < kend; k0 += 32) {
    const unsigned short* tr; int off, sI;
    if (k0 < 256)       { tr = tr0; off = 0;    sI = 0; }
    else if (k0 < 768)  { tr = tr1; off = 256;  sI = 1; }
    else if (k0 < 1792) { tr = tr2; off = 768;  sI = 2; }
    else                { tr = tr3; off = 1792; sI = 3; }

    f16x8 af[2];
    #pragma unroll
    for (int u = 0; u < 2; u++) {
      af[u] = *(const f16x8*)(tr + base[u][sI] + (k0 - off) + q * 8);
      if (zero[u][sI]) af[u] = (f16x8)(_Float16)0;
    }

    int slab = k0 >> 5;
    f16x8 Bh[8];
    #pragma unroll
    for (int nt = 0; nt < 8; nt++)
      Bh[nt] = BH[(size_t)(slab * 8 + nt) * 64 + lane];
    #pragma unroll
    for (int nt = 0; nt < 8; nt++) {
      acc[0][nt] = __builtin_amdgcn_mfma_f32_16x16x32_f16(af[0], Bh[nt], acc[0][nt], 0, 0, 0);
      acc[1][nt] = __builtin_amdgcn_mfma_f32_16x16x32_f16(af[1], Bh[nt], acc[1][nt], 0, 0, 0);
    }
  }

  #pragma unroll
  for (int u = 0; u < 2; u++)
    #pragma unroll
    for (int nt = 0; nt < 8; nt++)
      #pragma unroll
      for (int r = 0; r < 4; r++) {
        int row = m0 + (wave * 2 + u) * 16 + q * 4 + r;
        if (row < R_)
          part[((size_t)s * R_ + row) * 128 + nt * 16 + l15] = f16_bits(acc[u][nt][r]);
      }
}

// ---------------- reduce f16 partials(fp32 adds) + bias -> xcat f16 ----------------
__global__ __launch_bounds__(256) void k_reduce(
    const unsigned short* __restrict__ part, const float* __restrict__ lin_b,
    const float* __restrict__ vf, const float* __restrict__ pos,
    unsigned short* __restrict__ xcat, int nsplit) {
  int grp = threadIdx.x >> 5, ln = threadIdx.x & 31;
  int row = blockIdx.x * 8 + grp;           // 1233*8 = 9864
  float4 acc = ((const float4*)lin_b)[ln];
  const f16x4* p4 = (const f16x4*)part;
  for (int s = 0; s < nsplit; s++) {
    f16x4 pv = p4[((size_t)s * R_ + row) * 32 + ln];
    acc.x += (float)pv[0]; acc.y += (float)pv[1];
    acc.z += (float)pv[2]; acc.w += (float)pv[3];
  }
  ushort4* xr = (ushort4*)(xcat + (size_t)row * 288);
  ushort4 o;
  o.x = f16_bits(acc.x); o.y = f16_bits(acc.y);
  o.z = f16_bits(acc.z); o.w = f16_bits(acc.w);
  xr[ln] = o;
  float4 vv = ((const float4*)vf)[(size_t)row * 32 + ln];
  o.x = f16_bits(vv.x); o.y = f16_bits(vv.y);
  o.z = f16_bits(vv.z); o.w = f16_bits(vv.w);
  xr[32 + ln] = o;
  if (ln < 8) {
    ushort4 z = make_ushort4(0, 0, 0, 0);
    if (ln == 0) {
      z.x = f16_bits(pos[(size_t)row * 3 + 0]);
      z.y = f16_bits(pos[(size_t)row * 3 + 1]);
      z.z = f16_bits(pos[(size_t)row * 3 + 2]);
    }
    xr[64 + ln] = z;
  }
}

// ============ f16 MFMA GEMM (32-row tiles, nt split across waves) ============
// wave: mt = wave&1 (row half), nh = wave>>1 (nt half: 4 nt each).
template<int SLABS>
__global__ __launch_bounds__(256) void k_gemm_mfma(
    const unsigned short* __restrict__ X, int ldx,
    const unsigned short* __restrict__ wf,
    int matStride, const float* __restrict__ pb,
    unsigned short* __restrict__ o0, unsigned short* __restrict__ o1,
    unsigned short* __restrict__ o2) {
  int tid = threadIdx.x;
  int wave = tid >> 6, lane = tid & 63;
  int q = lane >> 4, l15 = lane & 15;
  int which = blockIdx.y;
  int m0 = blockIdx.x * 32;
  int mt = wave & 1, nh = wave >> 1;
  int mrow = m0 + mt * 16 + l15;
  int rowc = (mrow < R_) ? mrow : (R_ - 1);
  const unsigned short* xrow = X + (size_t)rowc * ldx + q * 8;

  const f16x8* BH = (const f16x8*)(wf + (size_t)which * matStride);

  f32x4 acc[4];
  #pragma unroll
  for (int t2 = 0; t2 < 4; t2++) acc[t2] = (f32x4){0.f, 0.f, 0.f, 0.f};

  #pragma unroll 1
  for (int slab = 0; slab < SLABS; slab++) {
    f16x8 af = *(const f16x8*)(xrow + slab * 32);
    f16x8 Bh[4];
    #pragma unroll
    for (int t2 = 0; t2 < 4; t2++)
      Bh[t2] = BH[(size_t)(slab * 8 + nh * 4 + t2) * 64 + lane];
    #pragma unroll
    for (int t2 = 0; t2 < 4; t2++)
      acc[t2] = __builtin_amdgcn_mfma_f32_16x16x32_f16(af, Bh[t2], acc[t2], 0, 0, 0);
  }

  unsigned short* out = (which == 0) ? o0 : (which == 1) ? o1 : o2;
  #pragma unroll
  for (int t2 = 0; t2 < 4; t2++) {
    int col = (nh * 4 + t2) * 16 + l15;
    float bias = (pb != nullptr && which == 2) ? pb[col] : 0.f;
    #pragma unroll
    for (int r = 0; r < 4; r++) {
      int row = m0 + mt * 16 + q * 4 + r;
      if (row < R_) out[(size_t)row * 128 + col] = f16_bits(acc[t2][r] + bias);
    }
  }
}

// ============ fused SpMM -> LDS -> GEMM (16 rows/block: 617 blocks, tail-friendly) ============
// Phase A: h = [skip? +] relu(s + A@t) for 16 rows, EXACT k_spmm arithmetic, -> LDS f16.
// Phase B: out[which] = h @ W[which] (+pb for which==2); 4 waves each own 2 nt-cols.
// Bit-identical to the separate spmm+gemm pair.
template<int NW>
__global__ __launch_bounds__(256) void k_fuse(
    const unsigned short* __restrict__ s_in,
    const unsigned short* __restrict__ t_in,
    const unsigned short* __restrict__ skip_in,
    const int* __restrict__ cols, const int* __restrict__ cnts,
    const unsigned short* __restrict__ wf, const float* __restrict__ pb,
    unsigned short* __restrict__ o0, unsigned short* __restrict__ o1,
    unsigned short* __restrict__ o2) {
  __shared__ unsigned short hsm[16][136];   // +8 pad: row stride 272B
  int tid = threadIdx.x;
  int r0 = blockIdx.x * 16;

  // ---- phase A: gather 16 rows into LDS (8 groups x 2 rows) ----
  {
    int grp = tid >> 5, ln = tid & 31;
    const f16x4* s4 = (const f16x4*)s_in;
    const f16x4* t4 = (const f16x4*)t_in;
    #pragma unroll 1
    for (int rr = 0; rr < 2; rr++) {
      int lrow = grp * 2 + rr;
      int row = r0 + lrow;
      int rowc = (row < R_) ? row : (R_ - 1);
      int b = rowc / N_;
      size_t tbase = (size_t)b * N_;
      const int* cp = cols + (size_t)rowc * ELLW;
      int4 ci0 = *(const int4*)cp;
      int4 ci1 = *(const int4*)(cp + 4);
      int4 ci2 = *(const int4*)(cp + 8);
      int cnt = cnts[rowc];
      f16x4 sv = s4[(size_t)rowc*32 + ln];
      float4 acc = make_float4((float)sv[0], (float)sv[1], (float)sv[2], (float)sv[3]);
      int idx[12] = {ci0.x, ci0.y, ci0.z, ci0.w, ci1.x, ci1.y, ci1.z, ci1.w,
                     ci2.x, ci2.y, ci2.z, ci2.w};
      f16x4 g[12];
      #pragma unroll
      for (int i = 0; i < 12; i++) {
        int c = idx[i];
        c = (c >= 0 && c < N_) ? c : 0;
        g[i] = t4[(tbase + c)*32 + ln];
      }
      #pragma unroll
      for (int i = 0; i < 12; i++) {
        if (i < cnt) {
          acc.x += (float)g[i][0]; acc.y += (float)g[i][1];
          acc.z += (float)g[i][2]; acc.w += (float)g[i][3];
        }
      }
      for (int i = 12; i < cnt; i++) {
        f16x4 v = t4[(tbase + cp[i])*32 + ln];
        acc.x += (float)v[0]; acc.y += (float)v[1];
        acc.z += (float)v[2]; acc.w += (float)v[3];
      }
      acc.x = fmaxf(acc.x, 0.f); acc.y = fmaxf(acc.y, 0.f);
      acc.z = fmaxf(acc.z, 0.f); acc.w = fmaxf(acc.w, 0.f);
      if (skip_in) {
        f16x4 sk = ((const f16x4*)skip_in)[(size_t)rowc*32 + ln];
        acc.x += (float)sk[0]; acc.y += (float)sk[1];
        acc.z += (float)sk[2]; acc.w += (float)sk[3];
      }
      ushort4 o;
      o.x = f16_bits(acc.x); o.y = f16_bits(acc.y);
      o.z = f16_bits(acc.z); o.w = f16_bits(acc.w);
      *(ushort4*)&hsm[lrow][ln * 4] = o;
    }
  }
  __syncthreads();

  // ---- phase B: MFMA from LDS; wave nh owns nt = wave*2 + {0,1} ----
  int wave = tid >> 6, lane = tid & 63;
  int q = lane >> 4, l15 = lane & 15;
  const unsigned short* xrow = &hsm[l15][q * 8];

  #pragma unroll 1
  for (int which = 0; which < NW; which++) {
    const f16x8* BH = (const f16x8*)(wf + (size_t)which * 16384);
    f32x4 acc[2];
    #pragma unroll
    for (int t2 = 0; t2 < 2; t2++) acc[t2] = (f32x4){0.f, 0.f, 0.f, 0.f};
    #pragma unroll
    for (int slab = 0; slab < 4; slab++) {
      f16x8 af = *(const f16x8*)(xrow + slab * 32);
      f16x8 Bh[2];
      #pragma unroll
      for (int t2 = 0; t2 < 2; t2++)
        Bh[t2] = BH[(size_t)(slab * 8 + wave * 2 + t2) * 64 + lane];
      #pragma unroll
      for (int t2 = 0; t2 < 2; t2++)
        acc[t2] = __builtin_amdgcn_mfma_f32_16x16x32_f16(af, Bh[t2], acc[t2], 0, 0, 0);
    }
    unsigned short* out = (which == 0) ? o0 : (which == 1) ? o1 : o2;
    #pragma unroll
    for (int t2 = 0; t2 < 2; t2++) {
      int col = (wave * 2 + t2) * 16 + l15;
      float bias = (pb != nullptr && which == 2) ? pb[col] : 0.f;
      #pragma unroll
      for (int r = 0; r < 4; r++) {
        int row = r0 + q * 4 + r;
        if (row < R_) out[(size_t)row * 128 + col] = f16_bits(acc[t2][r] + bias);
      }
    }
  }
}

// ---------------- SpMM (f16 in/out, fp32 adds): out = [skip +] relu(s + A@t) ----------------
__global__ __launch_bounds__(256) void k_spmm(
    const unsigned short* __restrict__ sb, const unsigned short* __restrict__ tb,
    const int* __restrict__ cols, const int* __restrict__ cnts,
    const unsigned short* __restrict__ skipb, unsigned short* __restrict__ outb,
    const float* __restrict__ gw0, const float* __restrict__ gw1,
    unsigned short* __restrict__ gsb, unsigned short* __restrict__ gtb, int fuse_gf) {
  int tid = threadIdx.x;
  int grp = tid >> 5, ln = tid & 31;
  int row = blockIdx.x * 8 + grp;           // 1233 * 8 = 9864 exact
  int b = row / N_;
  size_t tbase = (size_t)b * N_;
  const f16x4* sb4 = (const f16x4*)sb;
  const f16x4* tb4 = (const f16x4*)tb;
  const int* cp = cols + (size_t)row * ELLW;
  int4 ci0 = *(const int4*)cp;
  int4 ci1 = *(const int4*)(cp + 4);
  int4 ci2 = *(const int4*)(cp + 8);
  int cnt = cnts[row];
  f16x4 sv = sb4[(size_t)row*32 + ln];
  float4 acc = make_float4((float)sv[0], (float)sv[1], (float)sv[2], (float)sv[3]);
  int idx[12] = {ci0.x, ci0.y, ci0.z, ci0.w, ci1.x, ci1.y, ci1.z, ci1.w,
                 ci2.x, ci2.y, ci2.z, ci2.w};
  f16x4 g[12];
  #pragma unroll
  for (int i = 0; i < 12; i++) {
    int c = idx[i];
    c = (c >= 0 && c < N_) ? c : 0;
    g[i] = tb4[(tbase + c)*32 + ln];
  }
  #pragma unroll
  for (int i = 0; i < 12; i++) {
    if (i < cnt) {
      acc.x += (float)g[i][0]; acc.y += (float)g[i][1];
      acc.z += (float)g[i][2]; acc.w += (float)g[i][3];
    }
  }
  for (int i = 12; i < cnt; i++) {
    f16x4 v = tb4[(tbase + cp[i])*32 + ln];
    acc.x += (float)v[0]; acc.y += (float)v[1];
    acc.z += (float)v[2]; acc.w += (float)v[3];
  }
  acc.x = fmaxf(acc.x, 0.f); acc.y = fmaxf(acc.y, 0.f);
  acc.z = fmaxf(acc.z, 0.f); acc.w = fmaxf(acc.w, 0.f);
  if (skipb) {
    f16x4 sk = ((const f16x4*)skipb)[(size_t)row*32 + ln];
    acc.x += (float)sk[0]; acc.y += (float)sk[1];
    acc.z += (float)sk[2]; acc.w += (float)sk[3];
  }
  if (!fuse_gf) {
    ushort4 o;
    o.x = f16_bits(acc.x); o.y = f16_bits(acc.y);
    o.z = f16_bits(acc.z); o.w = f16_bits(acc.w);
    ((ushort4*)outb)[(size_t)row*32 + ln] = o;
    return;
  }
  float av[4] = {acc.x, acc.y, acc.z, acc.w};
  int j0 = ln * 4;
  float p0 = 0.f, p1 = 0.f, p2 = 0.f, q0 = 0.f, q1 = 0.f, q2 = 0.f;
  #pragma unroll
  for (int u = 0; u < 4; u++) {
    int j = j0 + u;
    p0 += av[u] * gw0[j*3+0]; p1 += av[u] * gw0[j*3+1]; p2 += av[u] * gw0[j*3+2];
    q0 += av[u] * gw1[j*3+0]; q1 += av[u] * gw1[j*3+1]; q2 += av[u] * gw1[j*3+2];
  }
  #pragma unroll
  for (int off = 16; off >= 1; off >>= 1) {
    p0 += __shfl_xor(p0, off); p1 += __shfl_xor(p1, off); p2 += __shfl_xor(p2, off);
    q0 += __shfl_xor(q0, off); q1 += __shfl_xor(q1, off); q2 += __shfl_xor(q2, off);
  }
  if (ln == 0) {
    gsb[(size_t)row*128 + 0] = f16_bits(p0);
    gsb[(size_t)row*128 + 1] = f16_bits(p1);
    gsb[(size_t)row*128 + 2] = f16_bits(p2);
    gtb[(size_t)row*128 + 0] = f16_bits(q0);
    gtb[(size_t)row*128 + 1] = f16_bits(q1);
    gtb[(size_t)row*128 + 2] = f16_bits(q2);
  }
}

// ---------------- final: out = pos + tanh(relu(s + A@t)), f16 in, fp32 out ----------------
__global__ __launch_bounds__(256) void k_gf_final(
    const unsigned short* __restrict__ sb, const unsigned short* __restrict__ tb,
    const int* __restrict__ cols, const int* __restrict__ cnts,
    const float* __restrict__ pos, float* __restrict__ out) {
  int wave = threadIdx.x >> 6, lane = threadIdx.x & 63;
  int row = blockIdx.x * 4 + wave;          // grid 2466
  if (lane >= 3) return;
  int b = row / N_;
  size_t tbase = (size_t)b * N_;
  const int* cp = cols + (size_t)row * ELLW;
  int4 ci0 = *(const int4*)cp;
  int4 ci1 = *(const int4*)(cp + 4);
  int4 ci2 = *(const int4*)(cp + 8);
  int cnt = cnts[row];
  union { unsigned short u; _Float16 h; } cv;
  cv.u = sb[(size_t)row*128 + lane];
  float acc = (float)cv.h;
  int idx[12] = {ci0.x, ci0.y, ci0.z, ci0.w, ci1.x, ci1.y, ci1.z, ci1.w,
                 ci2.x, ci2.y, ci2.z, ci2.w};
  float g[12];
  #pragma unroll
  for (int i = 0; i < 12; i++) {
    int c = idx[i];
    c = (c >= 0 && c < N_) ? c : 0;
    cv.u = tb[(tbase + c)*128 + lane];
    g[i] = (float)cv.h;
  }
  #pragma unroll
  for (int i = 0; i < 12; i++)
    if (i < cnt) acc += g[i];
  for (int i = 12; i < cnt; i++) {
    cv.u = tb[(tbase + cp[i])*128 + lane];
    acc += (float)cv.h;
  }
  float v = tanhf(fmaxf(acc, 0.f));
  out[(size_t)row*3 + lane] = pos[(size_t)row*3 + lane] + v;
}

extern "C" void kernel_launch(void* const* d_in, const int* in_sizes, int n_in,
                              void* d_out, int out_size, void* d_ws, size_t ws_size,
                              hipStream_t stream) {
  const float* conv2_3 = (const float*)d_in[0];
  const float* conv3_4 = (const float*)d_in[1];
  const float* conv4_6 = (const float*)d_in[2];
  const float* conv5_3 = (const float*)d_in[3];
  const float* pos     = (const float*)d_in[4];
  const float* vf      = (const float*)d_in[5];
  const float* adj     = (const float*)d_in[6];
  const float* lin_w   = (const float*)d_in[7];
  const float* lin_b   = (const float*)d_in[8];
  const float* r_pb[3]  = {(const float*)d_in[10], (const float*)d_in[16], (const float*)d_in[22]};
  const float* gf_w0 = (const float*)d_in[27];
  const float* gf_w1 = (const float*)d_in[28];
  float* out = (float*)d_out;

  // ---- workspace layout (all segments 16B-aligned; everything f16 except ELL ints) ----
  const size_t ROWF    = (size_t)R_ * 128;        // elems per activation buffer
  const size_t XCATE   = (size_t)R_ * 288;
  const size_t LINW_E  = 491520;
  const size_t RESW_E  = 307200;

  unsigned short* trh0 = (unsigned short*)d_ws;
  unsigned short* trh1 = trh0 + (size_t)4*256*3136;
  unsigned short* trh2 = trh1 + (size_t)4*512*784;
  unsigned short* trh3 = trh2 + (size_t)4*1024*196;
  int*   ell_cnt  = (int*)(trh3 + (size_t)4*2048*49);
  int*   ell_cols = ell_cnt + R_;
  unsigned short* whf = (unsigned short*)(ell_cols + (size_t)R_*ELLW);
  unsigned short* wrf = whf + LINW_E;
  unsigned short* part = wrf + RESW_E + 512;      // f16 split-K partials

  size_t fixed_h = 6021120 + 2*(size_t)R_*(ELLW+1) + LINW_E + RESW_E + 512;  // shorts
  size_t need8 = (fixed_h + (size_t)8*ROWF + XCATE + 8*ROWF + 1024) * 2;     // bytes
  int nsplit = (ws_size >= need8) ? 8 : 4;
  int kchunk = 3840 / nsplit;

  unsigned short* xcat = part + (size_t)nsplit * ROWF;
  unsigned short* sb   = xcat + XCATE;
  unsigned short* tb   = sb   + ROWF;
  unsigned short* sb2  = tb   + ROWF;
  unsigned short* tb2  = sb2  + ROWF;
  unsigned short* skA  = tb2  + ROWF;
  unsigned short* skB  = skA  + ROWF;
  unsigned short* gsb  = skB  + ROWF;
  unsigned short* gtb  = gsb  + ROWF;

  WMats wm;
  for (int rb = 0; rb < 3; rb++) {
    wm.p[rb*5 + 0] = (const float*)d_in[11 + 6*rb];  // w00
    wm.p[rb*5 + 1] = (const float*)d_in[12 + 6*rb];  // w01
    wm.p[rb*5 + 2] = (const float*)d_in[9  + 6*rb];  // pw
    wm.p[rb*5 + 3] = (const float*)d_in[13 + 6*rb];  // w10
    wm.p[rb*5 + 4] = (const float*)d_in[14 + 6*rb];  // w11
  }

  const int NFB = (R_ + 15) / 16;   // 617 fuse blocks
  const int NGB = (R_ + 31) / 32;   // 309 gemm row-tiles

  // D0: transposes(->f16) + ELL(4-wave scan, 1 block/row) + all W f16 splits
  k_pre<<<12228, 256, 0, stream>>>(conv2_3, conv3_4, conv4_6, conv5_3,
                                   trh0, trh1, trh2, trh3,
                                   adj, ell_cols, ell_cnt,
                                   lin_w, whf, wm, wrf);

  // D1: split-K f16 MFMA align GEMM (f16 partials)
  k_align_mfma<<<dim3(78, nsplit), 256, 0, stream>>>(trh0, trh1, trh2, trh3, pos,
                                                     whf, part, kchunk);

  // D2: reduce f16 partials + concat -> xcat
  k_reduce<<<1233, 256, 0, stream>>>(part, lin_b, vf, pos, xcat, nsplit);

  // D3: rb0 GEMM1: xcat @ {w00,w01,pw} -> sb,tb,skA
  k_gemm_mfma<9><<<dim3(NGB, 3), 256, 0, stream>>>(
      xcat, 288, wrf + 0, 36864, r_pb[0], sb, tb, skA);

  // D4: rb0 [spmm1+GEMM2]: h=relu(sb+A tb); h @ {w10,w11} -> sb2,tb2
  k_fuse<2><<<NFB, 256, 0, stream>>>(sb, tb, nullptr, ell_cols, ell_cnt,
                                     wrf + 110592, nullptr, sb2, tb2, nullptr);

  // D5: rb1 [spmm2+GEMM1]: x=skA+relu(sb2+A tb2); x @ {w00,w01,pw} -> sb,tb,skB
  k_fuse<3><<<NFB, 256, 0, stream>>>(sb2, tb2, skA, ell_cols, ell_cnt,
                                     wrf + 143360, r_pb[1], sb, tb, skB);

  // D6: rb1 [spmm1+GEMM2] -> sb2,tb2
  k_fuse<2><<<NFB, 256, 0, stream>>>(sb, tb, nullptr, ell_cols, ell_cnt,
                                     wrf + 192512, nullptr, sb2, tb2, nullptr);

  // D7: rb2 [spmm2+GEMM1]: x=skB+relu(...); -> sb,tb,skA
  k_fuse<3><<<NFB, 256, 0, stream>>>(sb2, tb2, skB, ell_cols, ell_cnt,
                                     wrf + 225280, r_pb[2], sb, tb, skA);

  // D8: rb2 [spmm1+GEMM2] -> sb2,tb2
  k_fuse<2><<<NFB, 256, 0, stream>>>(sb, tb, nullptr, ell_cols, ell_cnt,
                                     wrf + 274432, nullptr, sb2, tb2, nullptr);

  // D9: x_next = skA + relu(sb2 + A tb2); gsb = x@gf_w0, gtb = x@gf_w1
  k_spmm<<<1233, 256, 0, stream>>>(sb2, tb2, ell_cols, ell_cnt, skA, nullptr,
                                   gf_w0, gf_w1, gsb, gtb, 1);

  // D10: out = pos + tanh(relu(gsb + A gtb))
  k_gf_final<<<2466, 256, 0, stream>>>(gsb, gtb, ell_cols, ell_cnt, pos, out);
}

// Round 8
// 344.342 us; speedup vs baseline: 1.2187x; 1.0141x over previous
//
#include <hip/hip_runtime.h>
#include <cmath>

#define B_   4
#define N_   2466
#define R_   (B_*N_)     // 9864
#define ELLW 96

typedef _Float16 f16x8 __attribute__((ext_vector_type(8)));
typedef _Float16 f16x4 __attribute__((ext_vector_type(4)));
typedef __attribute__((ext_vector_type(4))) float f32x4;

__device__ __forceinline__ unsigned short f16_bits(float x) {
  union { _Float16 h; unsigned short u; } c;
  c.h = (_Float16)x;          // RNE
  return c.u;
}

struct WMats { const float* p[15]; };   // rb-major: w00,w01,pw,w10,w11

// Fragment-order layout (lin_w and res weights), f16 single-pass:
// e = ((slab*8 + nt)*64 + lane)*8 + j ; k = slab*32 + (lane>>4)*8 + j ; n = nt*16 + (lane&15)
// All activations AND split-K partials stored f16; all adds fp32. Rounding points
// and add ORDER identical to the baseline => bit-identical output.

// ============ fused pre-kernel: transposes(->f16) + ELL(4-wave scan) + W f16 splits ============
// grid: [0,1584) transpose | [1584,11448) ELL one block PER ROW | [11448,11928) whf | rest wrf
__global__ __launch_bounds__(256) void k_pre(
    const float* __restrict__ c2, const float* __restrict__ c3,
    const float* __restrict__ c4, const float* __restrict__ c5,
    unsigned short* __restrict__ t0, unsigned short* __restrict__ t1,
    unsigned short* __restrict__ t2, unsigned short* __restrict__ t3,
    const float* __restrict__ adj, int* __restrict__ cols, int* __restrict__ cnts,
    const float* __restrict__ lin_w,
    unsigned short* __restrict__ whf,
    WMats wm,
    unsigned short* __restrict__ wrf) {
  __shared__ float t[64][66];
  int bid = blockIdx.x;
  int tid = threadIdx.x;
  if (bid < 1584) {
    const float* in; unsigned short* out; int C, P, npb, ncb, rem;
    if (bid < 784)       { in = c2; out = t0; C = 256;  P = 3136; npb = 49; ncb = 4;  rem = bid; }
    else if (bid < 1200) { in = c3; out = t1; C = 512;  P = 784;  npb = 13; ncb = 8;  rem = bid - 784; }
    else if (bid < 1456) { in = c4; out = t2; C = 1024; P = 196;  npb = 4;  ncb = 16; rem = bid - 1200; }
    else                 { in = c5; out = t3; C = 2048; P = 49;   npb = 1;  ncb = 32; rem = bid - 1456; }
    int pb = rem % npb; int tq = rem / npb; int cb = tq % ncb; int b = tq / ncb;
    int c0 = cb * 64, p0 = pb * 64;
    #pragma unroll
    for (int i = 0; i < 8; i++) {
      int e = tid + i * 256;
      int c = e >> 5, f2 = e & 31;
      int p = p0 + f2 * 2;
      float2 v = make_float2(0.f, 0.f);
      const float* src = in + ((size_t)b * C + (c0 + c)) * P + p;
      if (p + 1 < P)      v = *(const float2*)src;
      else if (p < P)     v.x = *src;
      *(float2*)&t[c][f2 * 2] = v;
    }
    __syncthreads();
    int jj = tid & 15, c4i = jj * 4;
    #pragma unroll
    for (int pass = 0; pass < 4; pass++) {
      int pp = pass * 16 + (tid >> 4);
      int px = p0 + pp;
      if (px < P) {
        ushort4 o;
        o.x = f16_bits(t[c4i + 0][pp]);
        o.y = f16_bits(t[c4i + 1][pp]);
        o.z = f16_bits(t[c4i + 2][pp]);
        o.w = f16_bits(t[c4i + 3][pp]);
        *(ushort4*)&out[((size_t)b * P + px) * C + c0 + c4i] = o;
      }
    }
  } else if (bid < 11448) {
    // ---- ELL: one block per row; 4 waves cover j-ranges of 640; 2-pass scan ----
    int row = bid - 1584;
    int wv = tid >> 6, lane = tid & 63;
    const float* Ar = adj + (size_t)row * N_;
    int* cp = cols + (size_t)row * ELLW;
    unsigned long long below = (lane == 63) ? 0xFFFFFFFFFFFFFFFFull >> 1
                                            : ((1ull << lane) - 1ull);
    int jbeg = wv * 640;
    int jend = (jbeg + 640 < N_) ? jbeg + 640 : N_;
    unsigned long long m[3][4];
    int cnt = 0;
    #pragma unroll
    for (int i = 0; i < 3; i++) {
      int j0 = jbeg + i * 256 + lane * 4;
      float4 v = make_float4(0.f, 0.f, 0.f, 0.f);
      if (j0 + 3 < jend) {
        v = *(const float4*)&Ar[j0];
      } else {
        if (j0     < jend) v.x = Ar[j0];
        if (j0 + 1 < jend) v.y = Ar[j0+1];
        if (j0 + 2 < jend) v.z = Ar[j0+2];
      }
      m[i][0] = __ballot((j0     < jend) && (v.x != 0.f));
      m[i][1] = __ballot((j0 + 1 < jend) && (v.y != 0.f));
      m[i][2] = __ballot((j0 + 2 < jend) && (v.z != 0.f));
      m[i][3] = __ballot((j0 + 3 < jend) && (v.w != 0.f));
      cnt += __popcll(m[i][0]) + __popcll(m[i][1])
           + __popcll(m[i][2]) + __popcll(m[i][3]);
    }
    int* sc = (int*)&t[0][0];
    if (lane == 0) sc[wv] = cnt;
    __syncthreads();
    int base = 0;
    #pragma unroll
    for (int w2 = 0; w2 < 4; w2++) {
      int c = sc[w2];
      if (w2 < wv) base += c;
    }
    int tot = sc[0] + sc[1] + sc[2] + sc[3];
    int run = base;
    #pragma unroll
    for (int i = 0; i < 3; i++) {
      int j0 = jbeg + i * 256 + lane * 4;
      unsigned long long m0 = m[i][0], m1 = m[i][1], m2 = m[i][2], m3 = m[i][3];
      int pre = __popcll(m0 & below) + __popcll(m1 & below)
              + __popcll(m2 & below) + __popcll(m3 & below);
      bool nz0 = (m0 >> lane) & 1ull;
      bool nz1 = (m1 >> lane) & 1ull;
      bool nz2 = (m2 >> lane) & 1ull;
      bool nz3 = (m3 >> lane) & 1ull;
      int p0 = run + pre;
      int p1 = p0 + (nz0 ? 1 : 0);
      int p2 = p1 + (nz1 ? 1 : 0);
      int p3 = p2 + (nz2 ? 1 : 0);
      if (nz0 && p0 < ELLW) cp[p0] = j0;
      if (nz1 && p1 < ELLW) cp[p1] = j0 + 1;
      if (nz2 && p2 < ELLW) cp[p2] = j0 + 2;
      if (nz3 && p3 < ELLW) cp[p3] = j0 + 3;
      run += __popcll(m0) + __popcll(m1) + __popcll(m2) + __popcll(m3);
    }
    if (wv == 3 && lane == 0) cnts[row] = (tot > ELLW) ? ELLW : tot;
  } else if (bid < 11928) {
    int b = bid - 11448;
    int e0 = (b * 256 + tid) * 4;
    #pragma unroll
    for (int u = 0; u < 4; u++) {
      int e = e0 + u;
      int j = e & 7;
      int lane = (e >> 3) & 63;
      int nt = (e >> 9) & 7;
      int slab = e >> 12;
      int k = slab * 32 + ((lane >> 4) << 3) + j;
      int n = nt * 16 + (lane & 15);
      whf[e] = f16_bits(lin_w[(size_t)k * 128 + n]);
    }
  } else {
    int b = bid - 11928;
    int e0 = (b * 256 + tid) * 4;
    #pragma unroll
    for (int u = 0; u < 4; u++) {
      int e = e0 + u;
      int rb, mat, rem, K;
      if (e < 143360) {
        rb = 0;
        if (e < 110592) { mat = e / 36864; rem = e - mat * 36864; K = 259; }
        else { int tt = e - 110592; mat = 3 + tt / 16384; rem = tt & 16383; K = 128; }
      } else {
        int tt = e - 143360;
        rb = 1 + tt / 81920;
        int r2 = tt % 81920;
        mat = r2 / 16384; rem = r2 & 16383; K = 128;
      }
      int j = rem & 7, lane = (rem >> 3) & 63, nt = (rem >> 9) & 7, slab = rem >> 12;
      int k = slab * 32 + ((lane >> 4) << 3) + j;
      int n = nt * 16 + (lane & 15);
      float x = (k < K) ? wm.p[rb * 5 + mat][(size_t)k * 128 + n] : 0.f;
      wrf[e] = f16_bits(x);
    }
  }
}

// ============ split-K vertex-align gather (f16 maps) + f16 MFMA GEMM, f16 partials ============
__global__ __launch_bounds__(256) void k_align_mfma(
    const unsigned short* __restrict__ tr0, const unsigned short* __restrict__ tr1,
    const unsigned short* __restrict__ tr2, const unsigned short* __restrict__ tr3,
    const float* __restrict__ pos,
    const unsigned short* __restrict__ whf,
    unsigned short* __restrict__ part, int kchunk) {
  int tid  = threadIdx.x;
  int wave = tid >> 6, lane = tid & 63;
  int q    = lane >> 4, l15 = lane & 15;
  int m0   = blockIdx.x * 128;
  int s    = blockIdx.y;

  int zero[2][4]; int base[2][4];
  #pragma unroll
  for (int u = 0; u < 2; u++) {
    int mrow = m0 + (wave * 2 + u) * 16 + l15;
    int rowc = (mrow < R_) ? mrow : 0;
    int b = rowc / N_;
    float px = pos[rowc*3+0], py = pos[rowc*3+1], pz = pos[rowc*3+2];
    float hh = fminf(fmaxf(248.f*(py/pz)    + 111.5f, 0.f), 223.f);
    float wc = fminf(fmaxf(248.f*(px/(-pz)) + 111.5f, 0.f), 223.f);
    const int Sarr[4] = {56, 28, 14, 7};
    const int Carr[4] = {256, 512, 1024, 2048};
    #pragma unroll
    for (int sc = 0; sc < 4; sc++) {
      int S = Sarr[sc], C = Carr[sc];
      float dv = 224.f / (float)S;
      float x = hh / dv, y = wc / dv;
      int x1 = (int)floorf(x), y1 = (int)floorf(y);
      int x2 = min((int)ceilf(x), S - 1), y2 = min((int)ceilf(y), S - 1);
      int w = (x2 - x1) * (y2 - y1);              // ∈ {0,1}
      zero[u][sc] = (mrow >= R_) || (w == 0);
      base[u][sc] = (b * S * S + x1 * S + y1) * C;
    }
  }

  f32x4 acc[2][8];
  #pragma unroll
  for (int u = 0; u < 2; u++)
    #pragma unroll
    for (int nt = 0; nt < 8; nt++) acc[u][nt] = (f32x4){0.f, 0.f, 0.f, 0.f};

  const f16x8* BH = (const f16x8*)whf;

  int kbeg = s * kchunk, kend = kbeg + kchunk;
  #pragma unroll 1
  for (int k0 = kbeg; k0 < kend; k0 += 32) {
    const unsigned short* tr; int off, sI;
    if (k0 < 256)       { tr = tr0; off = 0;    sI = 0; }
    else if (k0 < 768)  { tr = tr1; off = 256;  sI = 1; }
    else if (k0 < 1792) { tr = tr2; off = 768;  sI = 2; }
    else                { tr = tr3; off = 1792; sI = 3; }

    f16x8 af[2];
    #pragma unroll
    for (int u = 0; u < 2; u++) {
      af[u] = *(const f16x8*)(tr + base[u][sI] + (k0 - off) + q * 8);
      if (zero[u][sI]) af[u] = (f16x8)(_Float16)0;
    }

    int slab = k0 >> 5;
    f16x8 Bh[8];
    #pragma unroll
    for (int nt = 0; nt < 8; nt++)
      Bh[nt] = BH[(size_t)(slab * 8 + nt) * 64 + lane];
    #pragma unroll
    for (int nt = 0; nt < 8; nt++) {
      acc[0][nt] = __builtin_amdgcn_mfma_f32_16x16x32_f16(af[0], Bh[nt], acc[0][nt], 0, 0, 0);
      acc[1][nt] = __builtin_amdgcn_mfma_f32_16x16x32_f16(af[1], Bh[nt], acc[1][nt], 0, 0, 0);
    }
  }

  #pragma unroll
  for (int u = 0; u < 2; u++)
    #pragma unroll
    for (int nt = 0; nt < 8; nt++)
      #pragma unroll
      for (int r = 0; r < 4; r++) {
        int row = m0 + (wave * 2 + u) * 16 + q * 4 + r;
        if (row < R_)
          part[((size_t)s * R_ + row) * 128 + nt * 16 + l15] = f16_bits(acc[u][nt][r]);
      }
}

// ============ fused reduce -> LDS -> rb0 GEMM1 ============
// Phase A: xcat-row bits for 16 rows (EXACT k_reduce arithmetic: lin_b + Σs part
//          in s order, fp32 adds, f16 RNE; vf cast; pos in cols 256..258, zeros after)
//          into LDS [16][296] (592B stride: 16B-aligned b128 reads, 2-way banks=free).
// Phase B: {sb,tb,skA}[which] = X @ W[which] (+pb for which==2); 9 slabs; 4 waves x 2 nt.
// Bit-identical to the separate reduce+gemm pair (same per-element MFMA chain).
__global__ __launch_bounds__(256) void k_xgemm(
    const unsigned short* __restrict__ part, const float* __restrict__ lin_b,
    const float* __restrict__ vf, const float* __restrict__ pos, int nsplit,
    const unsigned short* __restrict__ wf, const float* __restrict__ pb,
    unsigned short* __restrict__ o0, unsigned short* __restrict__ o1,
    unsigned short* __restrict__ o2) {
  __shared__ unsigned short hsm[16][296];
  int tid = threadIdx.x;
  int r0 = blockIdx.x * 16;

  // ---- phase A: build 16 xcat rows in LDS (8 groups x 2 rows, 32 lanes coalesced) ----
  {
    int grp = tid >> 5, ln = tid & 31;
    const f16x4* p4 = (const f16x4*)part;
    #pragma unroll 1
    for (int rr = 0; rr < 2; rr++) {
      int lrow = grp * 2 + rr;
      int row = r0 + lrow;
      int rowc = (row < R_) ? row : (R_ - 1);
      float4 acc = ((const float4*)lin_b)[ln];
      for (int s = 0; s < nsplit; s++) {
        f16x4 pv = p4[((size_t)s * R_ + rowc) * 32 + ln];
        acc.x += (float)pv[0]; acc.y += (float)pv[1];
        acc.z += (float)pv[2]; acc.w += (float)pv[3];
      }
      ushort4 o;
      o.x = f16_bits(acc.x); o.y = f16_bits(acc.y);
      o.z = f16_bits(acc.z); o.w = f16_bits(acc.w);
      *(ushort4*)&hsm[lrow][ln * 4] = o;
      float4 vv = ((const float4*)vf)[(size_t)rowc * 32 + ln];
      o.x = f16_bits(vv.x); o.y = f16_bits(vv.y);
      o.z = f16_bits(vv.z); o.w = f16_bits(vv.w);
      *(ushort4*)&hsm[lrow][128 + ln * 4] = o;
      if (ln < 8) {
        ushort4 z = make_ushort4(0, 0, 0, 0);
        if (ln == 0) {
          z.x = f16_bits(pos[(size_t)rowc * 3 + 0]);
          z.y = f16_bits(pos[(size_t)rowc * 3 + 1]);
          z.z = f16_bits(pos[(size_t)rowc * 3 + 2]);
        }
        *(ushort4*)&hsm[lrow][256 + ln * 4] = z;
      }
    }
  }
  __syncthreads();

  // ---- phase B: 9-slab MFMA from LDS; wave owns nt = wave*2 + {0,1} ----
  int wave = tid >> 6, lane = tid & 63;
  int q = lane >> 4, l15 = lane & 15;
  const unsigned short* xrow = &hsm[l15][q * 8];

  #pragma unroll 1
  for (int which = 0; which < 3; which++) {
    const f16x8* BH = (const f16x8*)(wf + (size_t)which * 36864);
    f32x4 acc[2];
    #pragma unroll
    for (int t2 = 0; t2 < 2; t2++) acc[t2] = (f32x4){0.f, 0.f, 0.f, 0.f};
    #pragma unroll
    for (int slab = 0; slab < 9; slab++) {
      f16x8 af = *(const f16x8*)(xrow + slab * 32);
      f16x8 Bh[2];
      #pragma unroll
      for (int t2 = 0; t2 < 2; t2++)
        Bh[t2] = BH[(size_t)(slab * 8 + wave * 2 + t2) * 64 + lane];
      #pragma unroll
      for (int t2 = 0; t2 < 2; t2++)
        acc[t2] = __builtin_amdgcn_mfma_f32_16x16x32_f16(af, Bh[t2], acc[t2], 0, 0, 0);
    }
    unsigned short* out = (which == 0) ? o0 : (which == 1) ? o1 : o2;
    #pragma unroll
    for (int t2 = 0; t2 < 2; t2++) {
      int col = (wave * 2 + t2) * 16 + l15;
      float bias = (which == 2) ? pb[col] : 0.f;
      #pragma unroll
      for (int r = 0; r < 4; r++) {
        int row = r0 + q * 4 + r;
        if (row < R_) out[(size_t)row * 128 + col] = f16_bits(acc[t2][r] + bias);
      }
    }
  }
}

// ============ fused SpMM -> LDS -> GEMM (16 rows/block) ============
template<int NW>
__global__ __launch_bounds__(256) void k_fuse(
    const unsigned short* __restrict__ s_in,
    const unsigned short* __restrict__ t_in,
    const unsigned short* __restrict__ skip_in,
    const int* __restrict__ cols, const int* __restrict__ cnts,
    const unsigned short* __restrict__ wf, const float* __restrict__ pb,
    unsigned short* __restrict__ o0, unsigned short* __restrict__ o1,
    unsigned short* __restrict__ o2) {
  __shared__ unsigned short hsm[16][136];   // +8 pad: row stride 272B
  int tid = threadIdx.x;
  int r0 = blockIdx.x * 16;

  // ---- phase A: gather 16 rows into LDS (8 groups x 2 rows) ----
  {
    int grp = tid >> 5, ln = tid & 31;
    const f16x4* s4 = (const f16x4*)s_in;
    const f16x4* t4 = (const f16x4*)t_in;
    #pragma unroll 1
    for (int rr = 0; rr < 2; rr++) {
      int lrow = grp * 2 + rr;
      int row = r0 + lrow;
      int rowc = (row < R_) ? row : (R_ - 1);
      int b = rowc / N_;
      size_t tbase = (size_t)b * N_;
      const int* cp = cols + (size_t)rowc * ELLW;
      int4 ci0 = *(const int4*)cp;
      int4 ci1 = *(const int4*)(cp + 4);
      int4 ci2 = *(const int4*)(cp + 8);
      int cnt = cnts[rowc];
      f16x4 sv = s4[(size_t)rowc*32 + ln];
      float4 acc = make_float4((float)sv[0], (float)sv[1], (float)sv[2], (float)sv[3]);
      int idx[12] = {ci0.x, ci0.y, ci0.z, ci0.w, ci1.x, ci1.y, ci1.z, ci1.w,
                     ci2.x, ci2.y, ci2.z, ci2.w};
      f16x4 g[12];
      #pragma unroll
      for (int i = 0; i < 12; i++) {
        int c = idx[i];
        c = (c >= 0 && c < N_) ? c : 0;
        g[i] = t4[(tbase + c)*32 + ln];
      }
      #pragma unroll
      for (int i = 0; i < 12; i++) {
        if (i < cnt) {
          acc.x += (float)g[i][0]; acc.y += (float)g[i][1];
          acc.z += (float)g[i][2]; acc.w += (float)g[i][3];
        }
      }
      for (int i = 12; i < cnt; i++) {
        f16x4 v = t4[(tbase + cp[i])*32 + ln];
        acc.x += (float)v[0]; acc.y += (float)v[1];
        acc.z += (float)v[2]; acc.w += (float)v[3];
      }
      acc.x = fmaxf(acc.x, 0.f); acc.y = fmaxf(acc.y, 0.f);
      acc.z = fmaxf(acc.z, 0.f); acc.w = fmaxf(acc.w, 0.f);
      if (skip_in) {
        f16x4 sk = ((const f16x4*)skip_in)[(size_t)rowc*32 + ln];
        acc.x += (float)sk[0]; acc.y += (float)sk[1];
        acc.z += (float)sk[2]; acc.w += (float)sk[3];
      }
      ushort4 o;
      o.x = f16_bits(acc.x); o.y = f16_bits(acc.y);
      o.z = f16_bits(acc.z); o.w = f16_bits(acc.w);
      *(ushort4*)&hsm[lrow][ln * 4] = o;
    }
  }
  __syncthreads();

  // ---- phase B: MFMA from LDS; wave owns nt = wave*2 + {0,1} ----
  int wave = tid >> 6, lane = tid & 63;
  int q = lane >> 4, l15 = lane & 15;
  const unsigned short* xrow = &hsm[l15][q * 8];

  #pragma unroll 1
  for (int which = 0; which < NW; which++) {
    const f16x8* BH = (const f16x8*)(wf + (size_t)which * 16384);
    f32x4 acc[2];
    #pragma unroll
    for (int t2 = 0; t2 < 2; t2++) acc[t2] = (f32x4){0.f, 0.f, 0.f, 0.f};
    #pragma unroll
    for (int slab = 0; slab < 4; slab++) {
      f16x8 af = *(const f16x8*)(xrow + slab * 32);
      f16x8 Bh[2];
      #pragma unroll
      for (int t2 = 0; t2 < 2; t2++)
        Bh[t2] = BH[(size_t)(slab * 8 + wave * 2 + t2) * 64 + lane];
      #pragma unroll
      for (int t2 = 0; t2 < 2; t2++)
        acc[t2] = __builtin_amdgcn_mfma_f32_16x16x32_f16(af, Bh[t2], acc[t2], 0, 0, 0);
    }
    unsigned short* out = (which == 0) ? o0 : (which == 1) ? o1 : o2;
    #pragma unroll
    for (int t2 = 0; t2 < 2; t2++) {
      int col = (wave * 2 + t2) * 16 + l15;
      float bias = (pb != nullptr && which == 2) ? pb[col] : 0.f;
      #pragma unroll
      for (int r = 0; r < 4; r++) {
        int row = r0 + q * 4 + r;
        if (row < R_) out[(size_t)row * 128 + col] = f16_bits(acc[t2][r] + bias);
      }
    }
  }
}

// ---------------- SpMM (f16 in/out, fp32 adds): out = [skip +] relu(s + A@t) ----------------
__global__ __launch_bounds__(256) void k_spmm(
    const unsigned short* __restrict__ sb, const unsigned short* __restrict__ tb,
    const int* __restrict__ cols, const int* __restrict__ cnts,
    const unsigned short* __restrict__ skipb, unsigned short* __restrict__ outb,
    const float* __restrict__ gw0, const float* __restrict__ gw1,
    unsigned short* __restrict__ gsb, unsigned short* __restrict__ gtb, int fuse_gf) {
  int tid = threadIdx.x;
  int grp = tid >> 5, ln = tid & 31;
  int row = blockIdx.x * 8 + grp;           // 1233 * 8 = 9864 exact
  int b = row / N_;
  size_t tbase = (size_t)b * N_;
  const f16x4* sb4 = (const f16x4*)sb;
  const f16x4* tb4 = (const f16x4*)tb;
  const int* cp = cols + (size_t)row * ELLW;
  int4 ci0 = *(const int4*)cp;
  int4 ci1 = *(const int4*)(cp + 4);
  int4 ci2 = *(const int4*)(cp + 8);
  int cnt = cnts[row];
  f16x4 sv = sb4[(size_t)row*32 + ln];
  float4 acc = make_float4((float)sv[0], (float)sv[1], (float)sv[2], (float)sv[3]);
  int idx[12] = {ci0.x, ci0.y, ci0.z, ci0.w, ci1.x, ci1.y, ci1.z, ci1.w,
                 ci2.x, ci2.y, ci2.z, ci2.w};
  f16x4 g[12];
  #pragma unroll
  for (int i = 0; i < 12; i++) {
    int c = idx[i];
    c = (c >= 0 && c < N_) ? c : 0;
    g[i] = tb4[(tbase + c)*32 + ln];
  }
  #pragma unroll
  for (int i = 0; i < 12; i++) {
    if (i < cnt) {
      acc.x += (float)g[i][0]; acc.y += (float)g[i][1];
      acc.z += (float)g[i][2]; acc.w += (float)g[i][3];
    }
  }
  for (int i = 12; i < cnt; i++) {
    f16x4 v = tb4[(tbase + cp[i])*32 + ln];
    acc.x += (float)v[0]; acc.y += (float)v[1];
    acc.z += (float)v[2]; acc.w += (float)v[3];
  }
  acc.x = fmaxf(acc.x, 0.f); acc.y = fmaxf(acc.y, 0.f);
  acc.z = fmaxf(acc.z, 0.f); acc.w = fmaxf(acc.w, 0.f);
  if (skipb) {
    f16x4 sk = ((const f16x4*)skipb)[(size_t)row*32 + ln];
    acc.x += (float)sk[0]; acc.y += (float)sk[1];
    acc.z += (float)sk[2]; acc.w += (float)sk[3];
  }
  if (!fuse_gf) {
    ushort4 o;
    o.x = f16_bits(acc.x); o.y = f16_bits(acc.y);
    o.z = f16_bits(acc.z); o.w = f16_bits(acc.w);
    ((ushort4*)outb)[(size_t)row*32 + ln] = o;
    return;
  }
  float av[4] = {acc.x, acc.y, acc.z, acc.w};
  int j0 = ln * 4;
  float p0 = 0.f, p1 = 0.f, p2 = 0.f, q0 = 0.f, q1 = 0.f, q2 = 0.f;
  #pragma unroll
  for (int u = 0; u < 4; u++) {
    int j = j0 + u;
    p0 += av[u] * gw0[j*3+0]; p1 += av[u] * gw0[j*3+1]; p2 += av[u] * gw0[j*3+2];
    q0 += av[u] * gw1[j*3+0]; q1 += av[u] * gw1[j*3+1]; q2 += av[u] * gw1[j*3+2];
  }
  #pragma unroll
  for (int off = 16; off >= 1; off >>= 1) {
    p0 += __shfl_xor(p0, off); p1 += __shfl_xor(p1, off); p2 += __shfl_xor(p2, off);
    q0 += __shfl_xor(q0, off); q1 += __shfl_xor(q1, off); q2 += __shfl_xor(q2, off);
  }
  if (ln == 0) {
    gsb[(size_t)row*128 + 0] = f16_bits(p0);
    gsb[(size_t)row*128 + 1] = f16_bits(p1);
    gsb[(size_t)row*128 + 2] = f16_bits(p2);
    gtb[(size_t)row*128 + 0] = f16_bits(q0);
    gtb[(size_t)row*128 + 1] = f16_bits(q1);
    gtb[(size_t)row*128 + 2] = f16_bits(q2);
  }
}

// ---------------- final: out = pos + tanh(relu(s + A@t)), f16 in, fp32 out ----------------
__global__ __launch_bounds__(256) void k_gf_final(
    const unsigned short* __restrict__ sb, const unsigned short* __restrict__ tb,
    const int* __restrict__ cols, const int* __restrict__ cnts,
    const float* __restrict__ pos, float* __restrict__ out) {
  int wave = threadIdx.x >> 6, lane = threadIdx.x & 63;
  int row = blockIdx.x * 4 + wave;          // grid 2466
  if (lane >= 3) return;
  int b = row / N_;
  size_t tbase = (size_t)b * N_;
  const int* cp = cols + (size_t)row * ELLW;
  int4 ci0 = *(const int4*)cp;
  int4 ci1 = *(const int4*)(cp + 4);
  int4 ci2 = *(const int4*)(cp + 8);
  int cnt = cnts[row];
  union { unsigned short u; _Float16 h; } cv;
  cv.u = sb[(size_t)row*128 + lane];
  float acc = (float)cv.h;
  int idx[12] = {ci0.x, ci0.y, ci0.z, ci0.w, ci1.x, ci1.y, ci1.z, ci1.w,
                 ci2.x, ci2.y, ci2.z, ci2.w};
  float g[12];
  #pragma unroll
  for (int i = 0; i < 12; i++) {
    int c = idx[i];
    c = (c >= 0 && c < N_) ? c : 0;
    cv.u = tb[(tbase + c)*128 + lane];
    g[i] = (float)cv.h;
  }
  #pragma unroll
  for (int i = 0; i < 12; i++)
    if (i < cnt) acc += g[i];
  for (int i = 12; i < cnt; i++) {
    cv.u = tb[(tbase + cp[i])*128 + lane];
    acc += (float)cv.h;
  }
  float v = tanhf(fmaxf(acc, 0.f));
  out[(size_t)row*3 + lane] = pos[(size_t)row*3 + lane] + v;
}

extern "C" void kernel_launch(void* const* d_in, const int* in_sizes, int n_in,
                              void* d_out, int out_size, void* d_ws, size_t ws_size,
                              hipStream_t stream) {
  const float* conv2_3 = (const float*)d_in[0];
  const float* conv3_4 = (const float*)d_in[1];
  const float* conv4_6 = (const float*)d_in[2];
  const float* conv5_3 = (const float*)d_in[3];
  const float* pos     = (const float*)d_in[4];
  const float* vf      = (const float*)d_in[5];
  const float* adj     = (const float*)d_in[6];
  const float* lin_w   = (const float*)d_in[7];
  const float* lin_b   = (const float*)d_in[8];
  const float* r_pb[3]  = {(const float*)d_in[10], (const float*)d_in[16], (const float*)d_in[22]};
  const float* gf_w0 = (const float*)d_in[27];
  const float* gf_w1 = (const float*)d_in[28];
  float* out = (float*)d_out;

  // ---- workspace layout (all segments 16B-aligned; everything f16 except ELL ints) ----
  const size_t ROWF    = (size_t)R_ * 128;        // elems per activation buffer
  const size_t LINW_E  = 491520;
  const size_t RESW_E  = 307200;

  unsigned short* trh0 = (unsigned short*)d_ws;
  unsigned short* trh1 = trh0 + (size_t)4*256*3136;
  unsigned short* trh2 = trh1 + (size_t)4*512*784;
  unsigned short* trh3 = trh2 + (size_t)4*1024*196;
  int*   ell_cnt  = (int*)(trh3 + (size_t)4*2048*49);
  int*   ell_cols = ell_cnt + R_;
  unsigned short* whf = (unsigned short*)(ell_cols + (size_t)R_*ELLW);
  unsigned short* wrf = whf + LINW_E;
  unsigned short* part = wrf + RESW_E + 512;      // f16 split-K partials

  size_t fixed_h = 6021120 + 2*(size_t)R_*(ELLW+1) + LINW_E + RESW_E + 512;  // shorts
  size_t need8 = (fixed_h + (size_t)8*ROWF + 8*ROWF + 1024) * 2;             // bytes
  int nsplit = (ws_size >= need8) ? 8 : 4;
  int kchunk = 3840 / nsplit;

  unsigned short* sb   = part + (size_t)nsplit * ROWF;
  unsigned short* tb   = sb   + ROWF;
  unsigned short* sb2  = tb   + ROWF;
  unsigned short* tb2  = sb2  + ROWF;
  unsigned short* skA  = tb2  + ROWF;
  unsigned short* skB  = skA  + ROWF;
  unsigned short* gsb  = skB  + ROWF;
  unsigned short* gtb  = gsb  + ROWF;

  WMats wm;
  for (int rb = 0; rb < 3; rb++) {
    wm.p[rb*5 + 0] = (const float*)d_in[11 + 6*rb];  // w00
    wm.p[rb*5 + 1] = (const float*)d_in[12 + 6*rb];  // w01
    wm.p[rb*5 + 2] = (const float*)d_in[9  + 6*rb];  // pw
    wm.p[rb*5 + 3] = (const float*)d_in[13 + 6*rb];  // w10
    wm.p[rb*5 + 4] = (const float*)d_in[14 + 6*rb];  // w11
  }

  const int NFB = (R_ + 15) / 16;   // 617 blocks (xgemm + fuse)

  // D0: transposes(->f16) + ELL(4-wave scan, 1 block/row) + all W f16 splits
  k_pre<<<12228, 256, 0, stream>>>(conv2_3, conv3_4, conv4_6, conv5_3,
                                   trh0, trh1, trh2, trh3,
                                   adj, ell_cols, ell_cnt,
                                   lin_w, whf, wm, wrf);

  // D1: split-K f16 MFMA align GEMM (f16 partials)
  k_align_mfma<<<dim3(78, nsplit), 256, 0, stream>>>(trh0, trh1, trh2, trh3, pos,
                                                     whf, part, kchunk);

  // D2: [reduce+rb0 GEMM1]: X=[Σpart+lin_b | vf | pos] @ {w00,w01,pw} -> sb,tb,skA
  k_xgemm<<<NFB, 256, 0, stream>>>(part, lin_b, vf, pos, nsplit,
                                   wrf + 0, r_pb[0], sb, tb, skA);

  // D3: rb0 [spmm1+GEMM2]: h=relu(sb+A tb); h @ {w10,w11} -> sb2,tb2
  k_fuse<2><<<NFB, 256, 0, stream>>>(sb, tb, nullptr, ell_cols, ell_cnt,
                                     wrf + 110592, nullptr, sb2, tb2, nullptr);

  // D4: rb1 [spmm2+GEMM1]: x=skA+relu(sb2+A tb2); x @ {w00,w01,pw} -> sb,tb,skB
  k_fuse<3><<<NFB, 256, 0, stream>>>(sb2, tb2, skA, ell_cols, ell_cnt,
                                     wrf + 143360, r_pb[1], sb, tb, skB);

  // D5: rb1 [spmm1+GEMM2] -> sb2,tb2
  k_fuse<2><<<NFB, 256, 0, stream>>>(sb, tb, nullptr, ell_cols, ell_cnt,
                                     wrf + 192512, nullptr, sb2, tb2, nullptr);

  // D6: rb2 [spmm2+GEMM1]: x=skB+relu(...); -> sb,tb,skA
  k_fuse<3><<<NFB, 256, 0, stream>>>(sb2, tb2, skB, ell_cols, ell_cnt,
                                     wrf + 225280, r_pb[2], sb, tb, skA);

  // D7: rb2 [spmm1+GEMM2] -> sb2,tb2
  k_fuse<2><<<NFB, 256, 0, stream>>>(sb, tb, nullptr, ell_cols, ell_cnt,
                                     wrf + 274432, nullptr, sb2, tb2, nullptr);

  // D8: x_next = skA + relu(sb2 + A tb2); gsb = x@gf_w0, gtb = x@gf_w1
  k_spmm<<<1233, 256, 0, stream>>>(sb2, tb2, ell_cols, ell_cnt, skA, nullptr,
                                   gf_w0, gf_w1, gsb, gtb, 1);

  // D9: out = pos + tanh(relu(gsb + A gtb))
  k_gf_final<<<2466, 256, 0, stream>>>(gsb, gtb, ell_cols, ell_cnt, pos, out);
}